// Round 17
// baseline (460.144 us; speedup 1.0000x reference)
//
#include <hip/hip_runtime.h>
#include <hip/hip_bf16.h>

#define NN 100000   // nodes
#define NE 1600000  // edges
#define NG 100      // graphs
#define NPG 1000    // nodes per graph
#define CE 16       // edge channels
#define HH 64       // hidden
#define BN_SCALE 0.99999500003749959f  // 1/sqrt(1+1e-5)
#define NB 512          // edge-chunk blocks
#define ECH (NE / NB)   // 3125 edges per chunk
#define NBIN 400        // dst bins: bin = dst/250 (4 bins per graph)

// LESSON (R3): f32 global atomicAdd on gfx950 = near-memory RMW (~35B HBM each).
// LESSON (R5): int global atomics ~40B each -> counting-sort CSR, no atomics.
// LESSON (R6): WAVE-BROADCAST edge processing (one edge per wave instr)
// serializes; thread-owned edges with LDS atomics are fine.
// LESSON (R8): W "register cache" via LDS stays in LDS; use global loads.
// LESSON (R9): un-unrolled load+add loops serialize at L2/L3 latency.
// LESSON (R10): guarded loads serialize when occupancy is LOW; clamp+cndmask.
// LESSON (R11/R12): allocator targets 84 VGPR; s_load returns out-of-order so
// scalar streaming can't pipeline. Node GEMMs belong on MFMA.
// LESSON (R13): give every build phase >=2k waves.
// LESSON (R14): wave-uniform scalar index loads are nearly free; don't trade
// them for redundant per-lane vector loads.
// LESSON (R15): at HIGH occupancy TLP hides serial tails; clamping to full
// 8-wide blocks ADDED ~40% redundant row loads and regressed. Only de-tail
// when the kernel is latency-bound AND occupancy-starved.

typedef __attribute__((ext_vector_type(8))) short bf16x8;
typedef __attribute__((ext_vector_type(4))) float f32x4;
union ABu { bf16x8 f; ushort u[8]; };

__device__ __forceinline__ ushort f2bf_rne(float f) {
  unsigned u = __float_as_uint(f);
  return (ushort)((u + 0x7FFFu + ((u >> 16) & 1u)) >> 16);
}

// ---- phase 1: per-chunk histogram over 400 dst-bins (LDS atomics only) ----
__global__ __launch_bounds__(256) void k_hist(const int* __restrict__ ei,
                                              int* __restrict__ hist,
                                              int* __restrict__ gtot) {
  __shared__ int h[NBIN];
  if (blockIdx.x == 0 && threadIdx.x == 0) gtot[NBIN] = 0;  // scan_a's counter
  for (int i = threadIdx.x; i < NBIN; i += 256) h[i] = 0;
  __syncthreads();
  int e0 = blockIdx.x * ECH;
  for (int i = threadIdx.x; i < ECH; i += 256) {
    int d = ei[NE + e0 + i];
    atomicAdd(&h[d / 250], 1);
  }
  __syncthreads();
  for (int i = threadIdx.x; i < NBIN; i += 256) hist[blockIdx.x * NBIN + i] = h[i];
}

// ---- phase 2: per-bin scan over chunk-counts; LAST block scans bin totals ----
__global__ __launch_bounds__(512) void k_scan_a(const int* __restrict__ hist,
                                                int* __restrict__ partial,
                                                int* __restrict__ gtot,
                                                int* __restrict__ gbase) {
  __shared__ int sv[512];
  __shared__ int last;
  int bin = blockIdx.x, t = threadIdx.x;
  int v = (t < NB) ? hist[t * NBIN + bin] : 0;
  sv[t] = v;
  __syncthreads();
  for (int o = 1; o < 512; o <<= 1) {
    int a = (t >= o) ? sv[t - o] : 0;
    __syncthreads();
    sv[t] += a;
    __syncthreads();
  }
  if (t < NB) partial[t * NBIN + bin] = sv[t] - v;
  if (t == 511) gtot[bin] = sv[511];
  // last-arriving block performs the cross-bin exclusive scan
  __threadfence();
  __syncthreads();
  if (t == 0) last = (atomicAdd(&gtot[NBIN], 1) == NBIN - 1) ? 1 : 0;
  __syncthreads();
  if (!last) return;
  int v2 = (t < NBIN) ? gtot[t] : 0;
  sv[t] = v2;
  __syncthreads();
  for (int o = 1; o < 512; o <<= 1) {
    int a = (t >= o) ? sv[t - o] : 0;
    __syncthreads();
    sv[t] += a;
    __syncthreads();
  }
  if (t < NBIN) gbase[t] = sv[t] - v2;
  if (t == 511) gbase[NBIN] = sv[511];
}

// ---- phase 3: scatter edges into bin segments (LDS cursors, 1x 8B store) ----
__global__ __launch_bounds__(256) void k_bfill(const int* __restrict__ ei,
                                               const int* __restrict__ partial,
                                               const int* __restrict__ gbase,
                                               unsigned long long* __restrict__ ebuf) {
  __shared__ int cur[NBIN];
  int b = blockIdx.x;
  for (int i = threadIdx.x; i < NBIN; i += 256)
    cur[i] = gbase[i] + partial[b * NBIN + i];
  __syncthreads();
  int e0 = b * ECH;
  for (int i = threadIdx.x; i < ECH; i += 256) {
    int e = e0 + i;
    int d = ei[NE + e], s = ei[e];
    int bin = d / 250;
    int gb = (bin >> 2) * 1000;
    unsigned long long pk = (unsigned long long)(unsigned)e << 32 |
                            (unsigned)((d - gb) << 10) | (unsigned)(s - gb);
    int pos = atomicAdd(&cur[bin], 1);
    ebuf[pos] = pk;
  }
}

// ---- phase 4: within-bin counting sort -> CSR, FUSED Se accumulation ----
// Per bin (250 nodes, ~4000 edges): histogram+scan -> rowptr/cnt; scatter
// ebuf2; thread-owned edges also load their 64B ea row and ds_add_f32 into
// se[250][17] (stride 17: (n*17+c)%32 spreads banks). Packed-bf16 Se16 out.
__global__ __launch_bounds__(1024) void k_nsort(
    const unsigned long long* __restrict__ ebuf, const int* __restrict__ gbase,
    const float* __restrict__ ea, unsigned* __restrict__ ebuf2,
    int* __restrict__ rowptr, int* __restrict__ cnt,
    ushort* __restrict__ Se16) {
  __shared__ float se[250 * 17];  // 17 KB
  __shared__ int h[250];
  __shared__ int cur[250];
  __shared__ int sv[256];
  int bin = blockIdx.x, t = threadIdx.x;
  int nb = bin * 250, lbase = (bin & 3) * 250;
  int lo = gbase[bin], hi = gbase[bin + 1];
  if (t < 250) h[t] = 0;
  for (int i = t; i < 250 * 17; i += 1024) se[i] = 0.f;
  __syncthreads();
  for (int i = lo + t; i < hi; i += 1024) {
    int dl = (int)((ebuf[i] >> 10) & 1023);
    atomicAdd(&h[dl - lbase], 1);
  }
  __syncthreads();
  int v = (t < 250) ? h[t] : 0;
  if (t < 256) sv[t] = v;
  __syncthreads();
  for (int o = 1; o < 256; o <<= 1) {
    int a = (t < 256 && t >= o) ? sv[t - o] : 0;
    __syncthreads();
    if (t < 256) sv[t] += a;
    __syncthreads();
  }
  if (t < 250) {
    int base = lo + sv[t] - v;  // exclusive
    rowptr[nb + t] = base;
    cur[t] = base;
    cnt[nb + t] = v;
  }
  if (bin == NBIN - 1 && t == 0) rowptr[NN] = hi;
  __syncthreads();
  for (int i = lo + t; i < hi; i += 1024) {
    unsigned long long u = ebuf[i];
    int dl = (int)((u >> 10) & 1023) - lbase;
    unsigned pk = (unsigned)(u >> 32) << 10 | (unsigned)(u & 1023);
    int pos = atomicAdd(&cur[dl], 1);
    ebuf2[pos] = pk;
    // fused Se: thread-owned edge, 64B ea row, 16 LDS f32 atomics
    unsigned eid = (unsigned)(u >> 32);
    const float4* er = (const float4*)(ea + (size_t)eid * CE);
    float4 e0 = er[0], e1 = er[1], e2 = er[2], e3 = er[3];
    float* sp = &se[dl * 17];
    atomicAdd(sp + 0, e0.x);  atomicAdd(sp + 1, e0.y);
    atomicAdd(sp + 2, e0.z);  atomicAdd(sp + 3, e0.w);
    atomicAdd(sp + 4, e1.x);  atomicAdd(sp + 5, e1.y);
    atomicAdd(sp + 6, e1.z);  atomicAdd(sp + 7, e1.w);
    atomicAdd(sp + 8, e2.x);  atomicAdd(sp + 9, e2.y);
    atomicAdd(sp + 10, e2.z); atomicAdd(sp + 11, e2.w);
    atomicAdd(sp + 12, e3.x); atomicAdd(sp + 13, e3.y);
    atomicAdd(sp + 14, e3.z); atomicAdd(sp + 15, e3.w);
  }
  __syncthreads();
  if (t < 1000) {  // node dl=t>>2, channel group cg=t&3 -> 8B packed store
    int dl = t >> 2, cg = t & 3;
    const float* sp = &se[dl * 17 + cg * 4];
    unsigned lo32 = (unsigned)f2bf_rne(sp[0]) | ((unsigned)f2bf_rne(sp[1]) << 16);
    unsigned hi32 = (unsigned)f2bf_rne(sp[2]) | ((unsigned)f2bf_rne(sp[3]) << 16);
    *(uint2*)(Se16 + (size_t)(nb + dl) * 16 + cg * 4) = make_uint2(lo32, hi32);
  }
}

// ---------------- per-layer node GEMM via MFMA (R12; templated) ------------
#define GEMM_TILES (NN / 16)  // 6250
#define GB 512
template <typename T>
__global__ __attribute__((amdgpu_waves_per_eu(2, 4))) __launch_bounds__(256)
void k_gemm(const T* __restrict__ x, const float* __restrict__ W,
            const float* __restrict__ b, const int* __restrict__ cnt,
            const ushort* __restrict__ Se16, ushort* __restrict__ y,
            ushort* __restrict__ z) {
  int lane = threadIdx.x & 63;
  int g = lane >> 4, r16 = lane & 15;

  ABu Bm[8][2];
  ABu Bs[4];
  float bias4[4];
#pragma unroll
  for (int t = 0; t < 8; ++t) {
    int col = t * 16 + r16;
    const float* wbase = W + (col < 64 ? 0 : 64 * 64);
    int c64 = col & 63;
#pragma unroll
    for (int h = 0; h < 2; ++h)
#pragma unroll
      for (int e = 0; e < 8; ++e) {
        int k = h * 32 + (e < 4 ? 0 : 16) + 4 * g + (e & 3);
        Bm[t][h].u[e] = f2bf_rne(wbase[k * 64 + c64]);
      }
  }
#pragma unroll
  for (int t = 0; t < 4; ++t) {
    int col = t * 16 + r16;
    float ws = 0.f;
#pragma unroll
    for (int m = 0; m < 16; ++m) ws += W[(128 + m) * 64 + col];
#pragma unroll
    for (int e = 0; e < 8; ++e) {
      int k = (e < 4 ? 0 : 16) + 4 * g + (e & 3);
      float v = (k < 16) ? W[(128 + k) * 64 + col] : (k == 16 ? ws : 0.f);
      Bs[t].u[e] = f2bf_rne(v);
    }
    bias4[t] = b[col];
  }

  int wid = (blockIdx.x << 2) + (threadIdx.x >> 6);
  int nw = GB * 4;
  for (int tt = wid; tt < GEMM_TILES; tt += nw) {
    int nb = tt * 16;
    ABu A0, A1, AS;
    if constexpr (sizeof(T) == 4) {
      const float* xr = (const float*)x + (size_t)(nb + r16) * HH;
      float4 f0 = *(const float4*)(xr + 4 * g);
      float4 f1 = *(const float4*)(xr + 16 + 4 * g);
      float4 f2 = *(const float4*)(xr + 32 + 4 * g);
      float4 f3 = *(const float4*)(xr + 48 + 4 * g);
      A0.u[0] = f2bf_rne(f0.x); A0.u[1] = f2bf_rne(f0.y);
      A0.u[2] = f2bf_rne(f0.z); A0.u[3] = f2bf_rne(f0.w);
      A0.u[4] = f2bf_rne(f1.x); A0.u[5] = f2bf_rne(f1.y);
      A0.u[6] = f2bf_rne(f1.z); A0.u[7] = f2bf_rne(f1.w);
      A1.u[0] = f2bf_rne(f2.x); A1.u[1] = f2bf_rne(f2.y);
      A1.u[2] = f2bf_rne(f2.z); A1.u[3] = f2bf_rne(f2.w);
      A1.u[4] = f2bf_rne(f3.x); A1.u[5] = f2bf_rne(f3.y);
      A1.u[6] = f2bf_rne(f3.z); A1.u[7] = f2bf_rne(f3.w);
    } else {
      const ushort* xr = (const ushort*)x + (size_t)(nb + r16) * HH;
      *(ushort4*)&A0.u[0] = *(const ushort4*)(xr + 4 * g);
      *(ushort4*)&A0.u[4] = *(const ushort4*)(xr + 16 + 4 * g);
      *(ushort4*)&A1.u[0] = *(const ushort4*)(xr + 32 + 4 * g);
      *(ushort4*)&A1.u[4] = *(const ushort4*)(xr + 48 + 4 * g);
    }
    const ushort* sr = Se16 + (size_t)(nb + r16) * 16;
    *(ushort4*)&AS.u[0] = *(const ushort4*)(sr + 4 * g);
    AS.u[4] = (g == 0) ? (ushort)0x3F80 : (ushort)0;  // k==16 -> 1.0
    AS.u[5] = 0; AS.u[6] = 0; AS.u[7] = 0;
    float dq[4];
#pragma unroll
    for (int q = 0; q < 4; ++q) dq[q] = (float)(cnt[nb + 4 * g + q] + 1);

    f32x4 accM[8], accS[4];
#pragma unroll
    for (int t = 0; t < 8; ++t) {
      f32x4 zz = {0.f, 0.f, 0.f, 0.f};
      zz = __builtin_amdgcn_mfma_f32_16x16x32_bf16(A0.f, Bm[t][0].f, zz, 0, 0, 0);
      accM[t] = __builtin_amdgcn_mfma_f32_16x16x32_bf16(A1.f, Bm[t][1].f, zz, 0, 0, 0);
    }
#pragma unroll
    for (int t = 0; t < 4; ++t) {
      f32x4 zz = {0.f, 0.f, 0.f, 0.f};
      accS[t] = __builtin_amdgcn_mfma_f32_16x16x32_bf16(AS.f, Bs[t].f, zz, 0, 0, 0);
    }
#pragma unroll
    for (int q = 0; q < 4; ++q) {
      size_t node = (size_t)(nb + 4 * g + q);
      ushort* zp = z + node * 64 + r16;
      ushort* yp = y + node * 64 + r16;
#pragma unroll
      for (int t = 0; t < 4; ++t) {
        float zv = dq[q] * (accM[t][q] + bias4[t]) + accS[t][q];
        zp[t * 16] = f2bf_rne(zv);
        yp[t * 16] = f2bf_rne(accM[4 + t][q]);
      }
    }
  }
}

// ---- per-layer gather: R13 EXACT (wave-per-node, 8-deep ILP + serial tail) ----
#define GTB 25000
__global__ __launch_bounds__(256) void k_gath3(
    const __hip_bfloat16* __restrict__ y, const __hip_bfloat16* __restrict__ z,
    const unsigned* __restrict__ ebuf2, const int* __restrict__ rowptr,
    const float* __restrict__ gamma, const float* __restrict__ beta,
    __hip_bfloat16* __restrict__ xn, float* __restrict__ emb) {
  int lane = threadIdx.x & 63;
  int orig = blockIdx.x;
  int blk = (orig & 7) * (GTB / 8) + (orig >> 3);
  int n0 = blk * 4 + (threadIdx.x >> 6);
  if (n0 >= NN) return;
  int n = __builtin_amdgcn_readfirstlane(n0);
  int lo = rowptr[n], hi = rowptr[n + 1];
  int deg = hi - lo;
  int gb = (n / NPG) * NPG;
  const unsigned* cl = ebuf2 + lo;
  const __hip_bfloat16* yg = y + (size_t)gb * HH;
  float acc = __bfloat162float(z[(size_t)n * HH + lane]) +
              __bfloat162float(y[(size_t)n * HH + lane]);
  int k = 0;
  for (; k + 8 <= deg; k += 8) {
    int s0 = cl[k] & 1023, s1 = cl[k + 1] & 1023;
    int s2 = cl[k + 2] & 1023, s3 = cl[k + 3] & 1023;
    int s4 = cl[k + 4] & 1023, s5 = cl[k + 5] & 1023;
    int s6 = cl[k + 6] & 1023, s7 = cl[k + 7] & 1023;
    float v0 = __bfloat162float(yg[(size_t)s0 * HH + lane]);
    float v1 = __bfloat162float(yg[(size_t)s1 * HH + lane]);
    float v2 = __bfloat162float(yg[(size_t)s2 * HH + lane]);
    float v3 = __bfloat162float(yg[(size_t)s3 * HH + lane]);
    float v4 = __bfloat162float(yg[(size_t)s4 * HH + lane]);
    float v5 = __bfloat162float(yg[(size_t)s5 * HH + lane]);
    float v6 = __bfloat162float(yg[(size_t)s6 * HH + lane]);
    float v7 = __bfloat162float(yg[(size_t)s7 * HH + lane]);
    acc += ((v0 + v1) + (v2 + v3)) + ((v4 + v5) + (v6 + v7));
  }
  for (; k < deg; ++k)
    acc += __bfloat162float(yg[(size_t)(cl[k] & 1023) * HH + lane]);
  acc = fmaxf(acc, 0.f);
  acc = gamma[lane] * acc * BN_SCALE + beta[lane];
  acc = fmaxf(acc, 0.f);
  xn[(size_t)n * HH + lane] = __float2bfloat16(acc);
  if (n % NPG == 0) emb[(n / NPG) * HH + lane] = acc;
}

// ---- readout: FUSED pool + MLP (1024 threads: 16-wave pooling, 4-way fc1) ----
__global__ __launch_bounds__(1024) void k_final(
    const __hip_bfloat16* __restrict__ xf, const float* __restrict__ emb,
    const float* __restrict__ nbr, const float* __restrict__ fc1w,
    const float* __restrict__ fc1b, const float* __restrict__ fc2w,
    const float* __restrict__ fc2b, float* __restrict__ out) {
  __shared__ float pp[16][64];
  __shared__ float feats[320];
  __shared__ float r1p[4][256];
  __shared__ float red[4][4];
  int g = blockIdx.x;
  int t = threadIdx.x;
  int lane = t & 63, wv = t >> 6;
  // pooling: 16 waves x 64 lanes over 1000 rows, 4-deep
  const __hip_bfloat16* base = xf + (size_t)g * NPG * HH;
  float acc = 0.f;
  int i = wv;
  for (; i + 48 < NPG; i += 64) {
    float v0 = __bfloat162float(base[(size_t)i * HH + lane]);
    float v1 = __bfloat162float(base[(size_t)(i + 16) * HH + lane]);
    float v2 = __bfloat162float(base[(size_t)(i + 32) * HH + lane]);
    float v3 = __bfloat162float(base[(size_t)(i + 48) * HH + lane]);
    acc += (v0 + v1) + (v2 + v3);
  }
  for (; i < NPG; i += 16) acc += __bfloat162float(base[(size_t)i * HH + lane]);
  pp[wv][lane] = acc;
  __syncthreads();
  if (t < 64) {
    float s = 0.f;
#pragma unroll
    for (int w = 0; w < 16; ++w) s += pp[w][t];
    feats[t] = s;
    feats[256 + t] = nbr[(size_t)g * HH + t];
  } else if (t < 256) {
    int j = t - 64;
    feats[64 + j] = emb[((size_t)(j >> 6) * NG + g) * HH + (j & 63)];
  } else if (t < 384) {
    int j = t - 256 + 128;  // embs 128..255
    feats[64 + j] = emb[((size_t)(j >> 6) * NG + g) * HH + (j & 63)];
  }
  __syncthreads();
  // fc1: 4 k-groups x 256 outputs; 8-deep ILP within each 80-k chunk
  int o = t & 255, tg = t >> 8;
  float a0 = 0.f, a1 = 0.f, a2 = 0.f, a3 = 0.f;
  const float* wp = fc1w + o;
  for (int k = tg * 80; k < tg * 80 + 80; k += 8) {
    float w0 = wp[(k + 0) * 256], w1 = wp[(k + 1) * 256];
    float w2 = wp[(k + 2) * 256], w3 = wp[(k + 3) * 256];
    float w4 = wp[(k + 4) * 256], w5 = wp[(k + 5) * 256];
    float w6 = wp[(k + 6) * 256], w7 = wp[(k + 7) * 256];
    a0 = fmaf(feats[k], w0, a0);
    a1 = fmaf(feats[k + 1], w1, a1);
    a2 = fmaf(feats[k + 2], w2, a2);
    a3 = fmaf(feats[k + 3], w3, a3);
    a0 = fmaf(feats[k + 4], w4, a0);
    a1 = fmaf(feats[k + 5], w5, a1);
    a2 = fmaf(feats[k + 6], w6, a2);
    a3 = fmaf(feats[k + 7], w7, a3);
  }
  r1p[tg][o] = (a0 + a1) + (a2 + a3);
  __syncthreads();
  if (t < 256) {
    float rv = fmaxf(fc1b[t] + ((r1p[0][t] + r1p[1][t]) + (r1p[2][t] + r1p[3][t])),
                     0.f);
    float p0 = rv * fc2w[t * 4 + 0];
    float p1 = rv * fc2w[t * 4 + 1];
    float p2 = rv * fc2w[t * 4 + 2];
    float p3 = rv * fc2w[t * 4 + 3];
#pragma unroll
    for (int oo = 1; oo < 64; oo <<= 1) {
      p0 += __shfl_xor(p0, oo);
      p1 += __shfl_xor(p1, oo);
      p2 += __shfl_xor(p2, oo);
      p3 += __shfl_xor(p3, oo);
    }
    if ((t & 63) == 0) {
      red[t >> 6][0] = p0; red[t >> 6][1] = p1;
      red[t >> 6][2] = p2; red[t >> 6][3] = p3;
    }
  }
  __syncthreads();
  if (t < 4)
    out[g * 4 + t] = fc2b[t] +
                     ((red[0][t] + red[1][t]) + (red[2][t] + red[3][t]));
}

extern "C" void kernel_launch(void* const* d_in, const int* in_sizes, int n_in,
                              void* d_out, int out_size, void* d_ws, size_t ws_size,
                              hipStream_t stream) {
  const float* x     = (const float*)d_in[0];
  const float* eattr = (const float*)d_in[1];
  const float* nbr   = (const float*)d_in[2];
  const float* W     = (const float*)d_in[3];
  const float* b     = (const float*)d_in[4];
  const float* gamma = (const float*)d_in[5];
  const float* beta  = (const float*)d_in[6];
  const float* fc1w  = (const float*)d_in[7];
  const float* fc1b  = (const float*)d_in[8];
  const float* fc2w  = (const float*)d_in[9];
  const float* fc2b  = (const float*)d_in[10];
  const int*   ei    = (const int*)d_in[11];
  float* out = (float*)d_out;
  (void)in_sizes; (void)n_in; (void)out_size; (void)ws_size;

  char* p = (char*)d_ws;
  size_t off = 0;
  auto alloc = [&](size_t bytes) {
    char* q = p + off;
    off += (bytes + 255) & ~(size_t)255;
    return q;
  };
  int* hist    = (int*)alloc((size_t)NB * NBIN * 4);
  int* partial = (int*)alloc((size_t)NB * NBIN * 4);
  int* gtot    = (int*)alloc((size_t)(NBIN + 1) * 4);  // [NBIN] = done-counter
  int* gbase   = (int*)alloc((size_t)(NBIN + 1) * 4);
  unsigned long long* ebuf = (unsigned long long*)alloc((size_t)NE * 8);
  unsigned* ebuf2 = (unsigned*)alloc((size_t)NE * 4);
  int* rowptr  = (int*)alloc((size_t)(NN + 1) * 4);
  ushort* Se16 = (ushort*)alloc((size_t)NN * 16 * 2);
  int*   cnt   = (int*)alloc((size_t)NN * 4);
  ushort* ybuf = (ushort*)alloc((size_t)NN * HH * 2);
  ushort* zbuf = (ushort*)alloc((size_t)NN * HH * 2);
  ushort* xA   = (ushort*)alloc((size_t)NN * HH * 2);
  ushort* xB   = (ushort*)alloc((size_t)NN * HH * 2);
  float* emb   = (float*)alloc((size_t)3 * NG * HH * 4);

  // CSR build + Se, 4 dispatches (zero global f32 atomics, no memsets)
  k_hist<<<NB, 256, 0, stream>>>(ei, hist, gtot);
  k_scan_a<<<NBIN, 512, 0, stream>>>(hist, partial, gtot, gbase);
  k_bfill<<<NB, 256, 0, stream>>>(ei, partial, gbase, ebuf);
  k_nsort<<<NBIN, 1024, 0, stream>>>(ebuf, gbase, eattr, ebuf2, rowptr, cnt, Se16);

  // layer 0: x (f32) -> xA
  k_gemm<float><<<GB, 256, 0, stream>>>(x, W, b, cnt, Se16, ybuf, zbuf);
  k_gath3<<<GTB, 256, 0, stream>>>((const __hip_bfloat16*)ybuf,
                                   (const __hip_bfloat16*)zbuf, ebuf2, rowptr,
                                   gamma, beta, (__hip_bfloat16*)xA, emb);
  // layer 1: xA -> xB
  k_gemm<ushort><<<GB, 256, 0, stream>>>(xA, W + 144 * 64, b + 64, cnt, Se16,
                                         ybuf, zbuf);
  k_gath3<<<GTB, 256, 0, stream>>>((const __hip_bfloat16*)ybuf,
                                   (const __hip_bfloat16*)zbuf, ebuf2, rowptr,
                                   gamma + 64, beta + 64, (__hip_bfloat16*)xB,
                                   emb + NG * HH);
  // layer 2: xB -> xA
  k_gemm<ushort><<<GB, 256, 0, stream>>>(xB, W + 2 * 144 * 64, b + 128, cnt,
                                         Se16, ybuf, zbuf);
  k_gath3<<<GTB, 256, 0, stream>>>((const __hip_bfloat16*)ybuf,
                                   (const __hip_bfloat16*)zbuf, ebuf2, rowptr,
                                   gamma + 128, beta + 128, (__hip_bfloat16*)xA,
                                   emb + 2 * NG * HH);

  k_final<<<NG, 1024, 0, stream>>>((const __hip_bfloat16*)xA, emb, nbr, fc1w,
                                   fc1b, fc2w, fc2b, out);
}

// Round 18
// 334.304 us; speedup vs baseline: 1.3764x; 1.3764x over previous
//
#include <hip/hip_runtime.h>
#include <hip/hip_bf16.h>

#define NN 100000   // nodes
#define NE 1600000  // edges
#define NG 100      // graphs
#define NPG 1000    // nodes per graph
#define CE 16       // edge channels
#define HH 64       // hidden
#define BN_SCALE 0.99999500003749959f  // 1/sqrt(1+1e-5)
#define NB 512          // edge-chunk blocks
#define ECH (NE / NB)   // 3125 edges per chunk
#define NBIN 400        // dst bins: bin = dst/250 (4 bins per graph)

// LESSON (R3): f32 global atomicAdd on gfx950 = near-memory RMW (~35B HBM each).
// LESSON (R5): int global atomics ~40B each -> counting-sort CSR, no atomics.
// LESSON (R6/R16): per-edge work must be SPREAD ACROSS LANES. One-edge-per-
// wave-instr broadcast (R6) and 16-serial-LDS-atomics-per-thread (R16) both
// serialize ~10x. k_se3's 4-lane-coalesced row quarters is the right shape.
// LESSON (R8): W "register cache" via LDS stays in LDS; use global loads.
// LESSON (R9): un-unrolled load+add loops serialize at L2/L3 latency.
// LESSON (R10): guarded loads serialize when occupancy is LOW; clamp+cndmask.
// LESSON (R11/R12): allocator targets 84 VGPR; s_load returns out-of-order so
// scalar streaming can't pipeline. Node GEMMs belong on MFMA.
// LESSON (R13): give every build phase >=2k waves.
// LESSON (R14): wave-uniform scalar index loads are nearly free.
// LESSON (R15): at HIGH occupancy TLP hides serial tails; don't add redundant
// full-width loads.

typedef __attribute__((ext_vector_type(8))) short bf16x8;
typedef __attribute__((ext_vector_type(4))) float f32x4;
union ABu { bf16x8 f; ushort u[8]; };

__device__ __forceinline__ ushort f2bf_rne(float f) {
  unsigned u = __float_as_uint(f);
  return (ushort)((u + 0x7FFFu + ((u >> 16) & 1u)) >> 16);
}

// ---- phase 1: per-chunk histogram over 400 dst-bins (LDS atomics only) ----
__global__ __launch_bounds__(256) void k_hist(const int* __restrict__ ei,
                                              int* __restrict__ hist,
                                              int* __restrict__ gtot) {
  __shared__ int h[NBIN];
  if (blockIdx.x == 0 && threadIdx.x == 0) gtot[NBIN] = 0;  // scan_a's counter
  for (int i = threadIdx.x; i < NBIN; i += 256) h[i] = 0;
  __syncthreads();
  int e0 = blockIdx.x * ECH;
  for (int i = threadIdx.x; i < ECH; i += 256) {
    int d = ei[NE + e0 + i];
    atomicAdd(&h[d / 250], 1);
  }
  __syncthreads();
  for (int i = threadIdx.x; i < NBIN; i += 256) hist[blockIdx.x * NBIN + i] = h[i];
}

// ---- phase 2: per-bin scan over chunk-counts; LAST block scans bin totals ----
__global__ __launch_bounds__(512) void k_scan_a(const int* __restrict__ hist,
                                                int* __restrict__ partial,
                                                int* __restrict__ gtot,
                                                int* __restrict__ gbase) {
  __shared__ int sv[512];
  __shared__ int last;
  int bin = blockIdx.x, t = threadIdx.x;
  int v = (t < NB) ? hist[t * NBIN + bin] : 0;
  sv[t] = v;
  __syncthreads();
  for (int o = 1; o < 512; o <<= 1) {
    int a = (t >= o) ? sv[t - o] : 0;
    __syncthreads();
    sv[t] += a;
    __syncthreads();
  }
  if (t < NB) partial[t * NBIN + bin] = sv[t] - v;
  if (t == 511) gtot[bin] = sv[511];
  __threadfence();
  __syncthreads();
  if (t == 0) last = (atomicAdd(&gtot[NBIN], 1) == NBIN - 1) ? 1 : 0;
  __syncthreads();
  if (!last) return;
  int v2 = (t < NBIN) ? gtot[t] : 0;
  sv[t] = v2;
  __syncthreads();
  for (int o = 1; o < 512; o <<= 1) {
    int a = (t >= o) ? sv[t - o] : 0;
    __syncthreads();
    sv[t] += a;
    __syncthreads();
  }
  if (t < NBIN) gbase[t] = sv[t] - v2;
  if (t == 511) gbase[NBIN] = sv[511];
}

// ---- phase 3: scatter edges into bin segments (LDS cursors, 1x 8B store) ----
__global__ __launch_bounds__(256) void k_bfill(const int* __restrict__ ei,
                                               const int* __restrict__ partial,
                                               const int* __restrict__ gbase,
                                               unsigned long long* __restrict__ ebuf) {
  __shared__ int cur[NBIN];
  int b = blockIdx.x;
  for (int i = threadIdx.x; i < NBIN; i += 256)
    cur[i] = gbase[i] + partial[b * NBIN + i];
  __syncthreads();
  int e0 = b * ECH;
  for (int i = threadIdx.x; i < ECH; i += 256) {
    int e = e0 + i;
    int d = ei[NE + e], s = ei[e];
    int bin = d / 250;
    int gb = (bin >> 2) * 1000;
    unsigned long long pk = (unsigned long long)(unsigned)e << 32 |
                            (unsigned)((d - gb) << 10) | (unsigned)(s - gb);
    int pos = atomicAdd(&cur[bin], 1);
    ebuf[pos] = pk;
  }
}

// ---- phase 4: within-bin counting sort by node -> per-node CSR (1024 thr) ----
__global__ __launch_bounds__(1024) void k_nsort(
    const unsigned long long* __restrict__ ebuf, const int* __restrict__ gbase,
    unsigned* __restrict__ ebuf2, int* __restrict__ rowptr,
    int* __restrict__ cnt) {
  __shared__ int h[250];
  __shared__ int cur[250];
  __shared__ int sv[256];
  int bin = blockIdx.x, t = threadIdx.x;
  int nb = bin * 250, lbase = (bin & 3) * 250;
  int lo = gbase[bin], hi = gbase[bin + 1];
  if (t < 250) h[t] = 0;
  __syncthreads();
  for (int i = lo + t; i < hi; i += 1024) {
    int dl = (int)((ebuf[i] >> 10) & 1023);
    atomicAdd(&h[dl - lbase], 1);
  }
  __syncthreads();
  int v = (t < 250) ? h[t] : 0;
  if (t < 256) sv[t] = v;
  __syncthreads();
  for (int o = 1; o < 256; o <<= 1) {
    int a = (t < 256 && t >= o) ? sv[t - o] : 0;
    __syncthreads();
    if (t < 256) sv[t] += a;
    __syncthreads();
  }
  if (t < 250) {
    int base = lo + sv[t] - v;  // exclusive
    rowptr[nb + t] = base;
    cur[t] = base;
    cnt[nb + t] = v;
  }
  if (bin == NBIN - 1 && t == 0) rowptr[NN] = hi;
  __syncthreads();
  for (int i = lo + t; i < hi; i += 1024) {
    unsigned long long u = ebuf[i];
    int dl = (int)((u >> 10) & 1023);
    unsigned pk = (unsigned)(u >> 32) << 10 | (unsigned)(u & 1023);
    int pos = atomicAdd(&cur[dl - lbase], 1);
    ebuf2[pos] = pk;
  }
}

// ---- Se: wave-per-node float4 gather (R10 shape); PACKED BF16 [n][16] ----
#define SEB 25000
__global__ __launch_bounds__(256) void k_se3(const unsigned* __restrict__ ebuf2,
                                             const int* __restrict__ rowptr,
                                             const float* __restrict__ ea,
                                             ushort* __restrict__ Se16) {
  int lane = threadIdx.x & 63;
  int slot = lane >> 2;  // edge slot 0..15
  int q = lane & 3;      // row quarter (4 channels)
  int orig = blockIdx.x;
  int blk = (orig & 7) * (SEB / 8) + (orig >> 3);
  int n0 = blk * 4 + (threadIdx.x >> 6);
  if (n0 >= NN) return;
  int n = __builtin_amdgcn_readfirstlane(n0);
  int lo = rowptr[n], hi = rowptr[n + 1];
  float aA0 = 0.f, aA1 = 0.f, aA2 = 0.f, aA3 = 0.f;
  float aB0 = 0.f, aB1 = 0.f, aB2 = 0.f, aB3 = 0.f;
  for (int k0 = lo; k0 < hi; k0 += 32) {
    int ka = k0 + slot, kb = k0 + 16 + slot;
    int kca = min(ka, NE - 1), kcb = min(kb, NE - 1);
    unsigned eida = ebuf2[kca] >> 10;
    unsigned eidb = ebuf2[kcb] >> 10;
    float4 va = *(const float4*)(ea + (size_t)eida * CE + q * 4);
    float4 vb = *(const float4*)(ea + (size_t)eidb * CE + q * 4);
    bool oka = ka < hi, okb = kb < hi;
    aA0 += oka ? va.x : 0.f;
    aA1 += oka ? va.y : 0.f;
    aA2 += oka ? va.z : 0.f;
    aA3 += oka ? va.w : 0.f;
    aB0 += okb ? vb.x : 0.f;
    aB1 += okb ? vb.y : 0.f;
    aB2 += okb ? vb.z : 0.f;
    aB3 += okb ? vb.w : 0.f;
  }
  float r0 = aA0 + aB0, r1 = aA1 + aB1, r2 = aA2 + aB2, r3 = aA3 + aB3;
#pragma unroll
  for (int o = 4; o < 64; o <<= 1) {
    r0 += __shfl_xor(r0, o);
    r1 += __shfl_xor(r1, o);
    r2 += __shfl_xor(r2, o);
    r3 += __shfl_xor(r3, o);
  }
  if (lane < 4) {
    unsigned lo32 = (unsigned)f2bf_rne(r0) | ((unsigned)f2bf_rne(r1) << 16);
    unsigned hi32 = (unsigned)f2bf_rne(r2) | ((unsigned)f2bf_rne(r3) << 16);
    *(uint2*)(Se16 + (size_t)n * 16 + lane * 4) = make_uint2(lo32, hi32);
  }
}

// ---------------- per-layer node GEMM via MFMA (R12; templated) ------------
#define GEMM_TILES (NN / 16)  // 6250
#define GB 512
template <typename T>
__global__ __attribute__((amdgpu_waves_per_eu(2, 4))) __launch_bounds__(256)
void k_gemm(const T* __restrict__ x, const float* __restrict__ W,
            const float* __restrict__ b, const int* __restrict__ cnt,
            const ushort* __restrict__ Se16, ushort* __restrict__ y,
            ushort* __restrict__ z) {
  int lane = threadIdx.x & 63;
  int g = lane >> 4, r16 = lane & 15;

  ABu Bm[8][2];
  ABu Bs[4];
  float bias4[4];
#pragma unroll
  for (int t = 0; t < 8; ++t) {
    int col = t * 16 + r16;
    const float* wbase = W + (col < 64 ? 0 : 64 * 64);
    int c64 = col & 63;
#pragma unroll
    for (int h = 0; h < 2; ++h)
#pragma unroll
      for (int e = 0; e < 8; ++e) {
        int k = h * 32 + (e < 4 ? 0 : 16) + 4 * g + (e & 3);
        Bm[t][h].u[e] = f2bf_rne(wbase[k * 64 + c64]);
      }
  }
#pragma unroll
  for (int t = 0; t < 4; ++t) {
    int col = t * 16 + r16;
    float ws = 0.f;
#pragma unroll
    for (int m = 0; m < 16; ++m) ws += W[(128 + m) * 64 + col];
#pragma unroll
    for (int e = 0; e < 8; ++e) {
      int k = (e < 4 ? 0 : 16) + 4 * g + (e & 3);
      float v = (k < 16) ? W[(128 + k) * 64 + col] : (k == 16 ? ws : 0.f);
      Bs[t].u[e] = f2bf_rne(v);
    }
    bias4[t] = b[col];
  }

  int wid = (blockIdx.x << 2) + (threadIdx.x >> 6);
  int nw = GB * 4;
  for (int tt = wid; tt < GEMM_TILES; tt += nw) {
    int nb = tt * 16;
    ABu A0, A1, AS;
    if constexpr (sizeof(T) == 4) {
      const float* xr = (const float*)x + (size_t)(nb + r16) * HH;
      float4 f0 = *(const float4*)(xr + 4 * g);
      float4 f1 = *(const float4*)(xr + 16 + 4 * g);
      float4 f2 = *(const float4*)(xr + 32 + 4 * g);
      float4 f3 = *(const float4*)(xr + 48 + 4 * g);
      A0.u[0] = f2bf_rne(f0.x); A0.u[1] = f2bf_rne(f0.y);
      A0.u[2] = f2bf_rne(f0.z); A0.u[3] = f2bf_rne(f0.w);
      A0.u[4] = f2bf_rne(f1.x); A0.u[5] = f2bf_rne(f1.y);
      A0.u[6] = f2bf_rne(f1.z); A0.u[7] = f2bf_rne(f1.w);
      A1.u[0] = f2bf_rne(f2.x); A1.u[1] = f2bf_rne(f2.y);
      A1.u[2] = f2bf_rne(f2.z); A1.u[3] = f2bf_rne(f2.w);
      A1.u[4] = f2bf_rne(f3.x); A1.u[5] = f2bf_rne(f3.y);
      A1.u[6] = f2bf_rne(f3.z); A1.u[7] = f2bf_rne(f3.w);
    } else {
      const ushort* xr = (const ushort*)x + (size_t)(nb + r16) * HH;
      *(ushort4*)&A0.u[0] = *(const ushort4*)(xr + 4 * g);
      *(ushort4*)&A0.u[4] = *(const ushort4*)(xr + 16 + 4 * g);
      *(ushort4*)&A1.u[0] = *(const ushort4*)(xr + 32 + 4 * g);
      *(ushort4*)&A1.u[4] = *(const ushort4*)(xr + 48 + 4 * g);
    }
    const ushort* sr = Se16 + (size_t)(nb + r16) * 16;
    *(ushort4*)&AS.u[0] = *(const ushort4*)(sr + 4 * g);
    AS.u[4] = (g == 0) ? (ushort)0x3F80 : (ushort)0;  // k==16 -> 1.0
    AS.u[5] = 0; AS.u[6] = 0; AS.u[7] = 0;
    float dq[4];
#pragma unroll
    for (int q = 0; q < 4; ++q) dq[q] = (float)(cnt[nb + 4 * g + q] + 1);

    f32x4 accM[8], accS[4];
#pragma unroll
    for (int t = 0; t < 8; ++t) {
      f32x4 zz = {0.f, 0.f, 0.f, 0.f};
      zz = __builtin_amdgcn_mfma_f32_16x16x32_bf16(A0.f, Bm[t][0].f, zz, 0, 0, 0);
      accM[t] = __builtin_amdgcn_mfma_f32_16x16x32_bf16(A1.f, Bm[t][1].f, zz, 0, 0, 0);
    }
#pragma unroll
    for (int t = 0; t < 4; ++t) {
      f32x4 zz = {0.f, 0.f, 0.f, 0.f};
      accS[t] = __builtin_amdgcn_mfma_f32_16x16x32_bf16(AS.f, Bs[t].f, zz, 0, 0, 0);
    }
#pragma unroll
    for (int q = 0; q < 4; ++q) {
      size_t node = (size_t)(nb + 4 * g + q);
      ushort* zp = z + node * 64 + r16;
      ushort* yp = y + node * 64 + r16;
#pragma unroll
      for (int t = 0; t < 4; ++t) {
        float zv = dq[q] * (accM[t][q] + bias4[t]) + accS[t][q];
        zp[t * 16] = f2bf_rne(zv);
        yp[t * 16] = f2bf_rne(accM[4 + t][q]);
      }
    }
  }
}

// ---- per-layer gather: R13 EXACT (wave-per-node, 8-deep ILP + serial tail) ----
#define GTB 25000
__global__ __launch_bounds__(256) void k_gath3(
    const __hip_bfloat16* __restrict__ y, const __hip_bfloat16* __restrict__ z,
    const unsigned* __restrict__ ebuf2, const int* __restrict__ rowptr,
    const float* __restrict__ gamma, const float* __restrict__ beta,
    __hip_bfloat16* __restrict__ xn, float* __restrict__ emb) {
  int lane = threadIdx.x & 63;
  int orig = blockIdx.x;
  int blk = (orig & 7) * (GTB / 8) + (orig >> 3);
  int n0 = blk * 4 + (threadIdx.x >> 6);
  if (n0 >= NN) return;
  int n = __builtin_amdgcn_readfirstlane(n0);
  int lo = rowptr[n], hi = rowptr[n + 1];
  int deg = hi - lo;
  int gb = (n / NPG) * NPG;
  const unsigned* cl = ebuf2 + lo;
  const __hip_bfloat16* yg = y + (size_t)gb * HH;
  float acc = __bfloat162float(z[(size_t)n * HH + lane]) +
              __bfloat162float(y[(size_t)n * HH + lane]);
  int k = 0;
  for (; k + 8 <= deg; k += 8) {
    int s0 = cl[k] & 1023, s1 = cl[k + 1] & 1023;
    int s2 = cl[k + 2] & 1023, s3 = cl[k + 3] & 1023;
    int s4 = cl[k + 4] & 1023, s5 = cl[k + 5] & 1023;
    int s6 = cl[k + 6] & 1023, s7 = cl[k + 7] & 1023;
    float v0 = __bfloat162float(yg[(size_t)s0 * HH + lane]);
    float v1 = __bfloat162float(yg[(size_t)s1 * HH + lane]);
    float v2 = __bfloat162float(yg[(size_t)s2 * HH + lane]);
    float v3 = __bfloat162float(yg[(size_t)s3 * HH + lane]);
    float v4 = __bfloat162float(yg[(size_t)s4 * HH + lane]);
    float v5 = __bfloat162float(yg[(size_t)s5 * HH + lane]);
    float v6 = __bfloat162float(yg[(size_t)s6 * HH + lane]);
    float v7 = __bfloat162float(yg[(size_t)s7 * HH + lane]);
    acc += ((v0 + v1) + (v2 + v3)) + ((v4 + v5) + (v6 + v7));
  }
  for (; k < deg; ++k)
    acc += __bfloat162float(yg[(size_t)(cl[k] & 1023) * HH + lane]);
  acc = fmaxf(acc, 0.f);
  acc = gamma[lane] * acc * BN_SCALE + beta[lane];
  acc = fmaxf(acc, 0.f);
  xn[(size_t)n * HH + lane] = __float2bfloat16(acc);
  if (n % NPG == 0) emb[(n / NPG) * HH + lane] = acc;
}

// ---- readout: FUSED pool + MLP (1024 threads: 16-wave pooling, 4-way fc1) ----
__global__ __launch_bounds__(1024) void k_final(
    const __hip_bfloat16* __restrict__ xf, const float* __restrict__ emb,
    const float* __restrict__ nbr, const float* __restrict__ fc1w,
    const float* __restrict__ fc1b, const float* __restrict__ fc2w,
    const float* __restrict__ fc2b, float* __restrict__ out) {
  __shared__ float pp[16][64];
  __shared__ float feats[320];
  __shared__ float r1p[4][256];
  __shared__ float red[4][4];
  int g = blockIdx.x;
  int t = threadIdx.x;
  int lane = t & 63, wv = t >> 6;
  const __hip_bfloat16* base = xf + (size_t)g * NPG * HH;
  float acc = 0.f;
  int i = wv;
  for (; i + 48 < NPG; i += 64) {
    float v0 = __bfloat162float(base[(size_t)i * HH + lane]);
    float v1 = __bfloat162float(base[(size_t)(i + 16) * HH + lane]);
    float v2 = __bfloat162float(base[(size_t)(i + 32) * HH + lane]);
    float v3 = __bfloat162float(base[(size_t)(i + 48) * HH + lane]);
    acc += (v0 + v1) + (v2 + v3);
  }
  for (; i < NPG; i += 16) acc += __bfloat162float(base[(size_t)i * HH + lane]);
  pp[wv][lane] = acc;
  __syncthreads();
  if (t < 64) {
    float s = 0.f;
#pragma unroll
    for (int w = 0; w < 16; ++w) s += pp[w][t];
    feats[t] = s;
    feats[256 + t] = nbr[(size_t)g * HH + t];
  } else if (t < 256) {
    int j = t - 64;
    feats[64 + j] = emb[((size_t)(j >> 6) * NG + g) * HH + (j & 63)];
  } else if (t < 384) {
    int j = t - 256 + 128;  // embs 128..255
    feats[64 + j] = emb[((size_t)(j >> 6) * NG + g) * HH + (j & 63)];
  }
  __syncthreads();
  int o = t & 255, tg = t >> 8;
  float a0 = 0.f, a1 = 0.f, a2 = 0.f, a3 = 0.f;
  const float* wp = fc1w + o;
  for (int k = tg * 80; k < tg * 80 + 80; k += 8) {
    float w0 = wp[(k + 0) * 256], w1 = wp[(k + 1) * 256];
    float w2 = wp[(k + 2) * 256], w3 = wp[(k + 3) * 256];
    float w4 = wp[(k + 4) * 256], w5 = wp[(k + 5) * 256];
    float w6 = wp[(k + 6) * 256], w7 = wp[(k + 7) * 256];
    a0 = fmaf(feats[k], w0, a0);
    a1 = fmaf(feats[k + 1], w1, a1);
    a2 = fmaf(feats[k + 2], w2, a2);
    a3 = fmaf(feats[k + 3], w3, a3);
    a0 = fmaf(feats[k + 4], w4, a0);
    a1 = fmaf(feats[k + 5], w5, a1);
    a2 = fmaf(feats[k + 6], w6, a2);
    a3 = fmaf(feats[k + 7], w7, a3);
  }
  r1p[tg][o] = (a0 + a1) + (a2 + a3);
  __syncthreads();
  if (t < 256) {
    float rv = fmaxf(fc1b[t] + ((r1p[0][t] + r1p[1][t]) + (r1p[2][t] + r1p[3][t])),
                     0.f);
    float p0 = rv * fc2w[t * 4 + 0];
    float p1 = rv * fc2w[t * 4 + 1];
    float p2 = rv * fc2w[t * 4 + 2];
    float p3 = rv * fc2w[t * 4 + 3];
#pragma unroll
    for (int oo = 1; oo < 64; oo <<= 1) {
      p0 += __shfl_xor(p0, oo);
      p1 += __shfl_xor(p1, oo);
      p2 += __shfl_xor(p2, oo);
      p3 += __shfl_xor(p3, oo);
    }
    if ((t & 63) == 0) {
      red[t >> 6][0] = p0; red[t >> 6][1] = p1;
      red[t >> 6][2] = p2; red[t >> 6][3] = p3;
    }
  }
  __syncthreads();
  if (t < 4)
    out[g * 4 + t] = fc2b[t] +
                     ((red[0][t] + red[1][t]) + (red[2][t] + red[3][t]));
}

extern "C" void kernel_launch(void* const* d_in, const int* in_sizes, int n_in,
                              void* d_out, int out_size, void* d_ws, size_t ws_size,
                              hipStream_t stream) {
  const float* x     = (const float*)d_in[0];
  const float* eattr = (const float*)d_in[1];
  const float* nbr   = (const float*)d_in[2];
  const float* W     = (const float*)d_in[3];
  const float* b     = (const float*)d_in[4];
  const float* gamma = (const float*)d_in[5];
  const float* beta  = (const float*)d_in[6];
  const float* fc1w  = (const float*)d_in[7];
  const float* fc1b  = (const float*)d_in[8];
  const float* fc2w  = (const float*)d_in[9];
  const float* fc2b  = (const float*)d_in[10];
  const int*   ei    = (const int*)d_in[11];
  float* out = (float*)d_out;
  (void)in_sizes; (void)n_in; (void)out_size; (void)ws_size;

  char* p = (char*)d_ws;
  size_t off = 0;
  auto alloc = [&](size_t bytes) {
    char* q = p + off;
    off += (bytes + 255) & ~(size_t)255;
    return q;
  };
  int* hist    = (int*)alloc((size_t)NB * NBIN * 4);
  int* partial = (int*)alloc((size_t)NB * NBIN * 4);
  int* gtot    = (int*)alloc((size_t)(NBIN + 1) * 4);  // [NBIN] = done-counter
  int* gbase   = (int*)alloc((size_t)(NBIN + 1) * 4);
  unsigned long long* ebuf = (unsigned long long*)alloc((size_t)NE * 8);
  unsigned* ebuf2 = (unsigned*)alloc((size_t)NE * 4);
  int* rowptr  = (int*)alloc((size_t)(NN + 1) * 4);
  ushort* Se16 = (ushort*)alloc((size_t)NN * 16 * 2);
  int*   cnt   = (int*)alloc((size_t)NN * 4);
  ushort* ybuf = (ushort*)alloc((size_t)NN * HH * 2);
  ushort* zbuf = (ushort*)alloc((size_t)NN * HH * 2);
  ushort* xA   = (ushort*)alloc((size_t)NN * HH * 2);
  ushort* xB   = (ushort*)alloc((size_t)NN * HH * 2);
  float* emb   = (float*)alloc((size_t)3 * NG * HH * 4);

  // CSR build via two-level counting sort (zero global f32 atomics, no memsets)
  k_hist<<<NB, 256, 0, stream>>>(ei, hist, gtot);
  k_scan_a<<<NBIN, 512, 0, stream>>>(hist, partial, gtot, gbase);
  k_bfill<<<NB, 256, 0, stream>>>(ei, partial, gbase, ebuf);
  k_nsort<<<NBIN, 1024, 0, stream>>>(ebuf, gbase, ebuf2, rowptr, cnt);
  k_se3<<<SEB, 256, 0, stream>>>(ebuf2, rowptr, eattr, Se16);

  // layer 0: x (f32) -> xA
  k_gemm<float><<<GB, 256, 0, stream>>>(x, W, b, cnt, Se16, ybuf, zbuf);
  k_gath3<<<GTB, 256, 0, stream>>>((const __hip_bfloat16*)ybuf,
                                   (const __hip_bfloat16*)zbuf, ebuf2, rowptr,
                                   gamma, beta, (__hip_bfloat16*)xA, emb);
  // layer 1: xA -> xB
  k_gemm<ushort><<<GB, 256, 0, stream>>>(xA, W + 144 * 64, b + 64, cnt, Se16,
                                         ybuf, zbuf);
  k_gath3<<<GTB, 256, 0, stream>>>((const __hip_bfloat16*)ybuf,
                                   (const __hip_bfloat16*)zbuf, ebuf2, rowptr,
                                   gamma + 64, beta + 64, (__hip_bfloat16*)xB,
                                   emb + NG * HH);
  // layer 2: xB -> xA
  k_gemm<ushort><<<GB, 256, 0, stream>>>(xB, W + 2 * 144 * 64, b + 128, cnt,
                                         Se16, ybuf, zbuf);
  k_gath3<<<GTB, 256, 0, stream>>>((const __hip_bfloat16*)ybuf,
                                   (const __hip_bfloat16*)zbuf, ebuf2, rowptr,
                                   gamma + 128, beta + 128, (__hip_bfloat16*)xA,
                                   emb + 2 * NG * HH);

  k_final<<<NG, 1024, 0, stream>>>((const __hip_bfloat16*)xA, emb, nbr, fc1w,
                                   fc1b, fc2w, fc2b, out);
}

// Round 19
// 252.476 us; speedup vs baseline: 1.8225x; 1.3241x over previous
//
#include <hip/hip_runtime.h>
#include <hip/hip_bf16.h>

#define NN 100000   // nodes
#define NE 1600000  // edges
#define NG 100      // graphs
#define NPG 1000    // nodes per graph
#define CE 16       // edge channels
#define HH 64       // hidden
#define BN_SCALE 0.99999500003749959f  // 1/sqrt(1+1e-5)
#define NB 512          // edge-chunk blocks
#define ECH (NE / NB)   // 3125 edges per chunk
#define NBIN 400        // dst bins: bin = dst/250 (4 bins per graph)

// LESSON (R3): f32 global atomicAdd on gfx950 = near-memory RMW (~35B HBM each).
// LESSON (R5): int global atomics ~40B each -> counting-sort CSR, no atomics.
// LESSON (R6/R16): per-edge work must be SPREAD ACROSS LANES; serial per-thread
// chains (16 LDS atomics, or one-edge-per-wave-instr) serialize ~10x.
// LESSON (R8): W "register cache" via LDS stays in LDS; use global loads.
// LESSON (R9): un-unrolled load+add loops serialize at L2/L3 latency.
// LESSON (R10): guarded loads serialize when occupancy is LOW; clamp+cndmask.
// LESSON (R11/R12): allocator targets 84 VGPR; s_load returns out-of-order.
// Node GEMMs belong on MFMA.
// LESSON (R13): give every build phase >=2k waves.
// LESSON (R14): wave-uniform scalar index loads are nearly free.
// LESSON (R15): at HIGH occupancy TLP hides serial tails.
// LESSON (R17): per-block __threadfence() x400 = 90us; last-block-done fusion
// loses. And strided LOADS stall while strided STORES don't: put the scatter
// on the producer (hist transposed) so the consumer reads coalesced.

typedef __attribute__((ext_vector_type(8))) short bf16x8;
typedef __attribute__((ext_vector_type(4))) float f32x4;
union ABu { bf16x8 f; ushort u[8]; };

__device__ __forceinline__ ushort f2bf_rne(float f) {
  unsigned u = __float_as_uint(f);
  return (ushort)((u + 0x7FFFu + ((u >> 16) & 1u)) >> 16);
}

// ---- phase 1: per-chunk histogram; TRANSPOSED store hist[bin][chunk] ----
__global__ __launch_bounds__(256) void k_hist(const int* __restrict__ ei,
                                              int* __restrict__ hist) {
  __shared__ int h[NBIN];
  for (int i = threadIdx.x; i < NBIN; i += 256) h[i] = 0;
  __syncthreads();
  int e0 = blockIdx.x * ECH;
  for (int i = threadIdx.x; i < ECH; i += 256) {
    int d = ei[NE + e0 + i];
    atomicAdd(&h[d / 250], 1);
  }
  __syncthreads();
  for (int i = threadIdx.x; i < NBIN; i += 256)
    hist[i * NB + blockIdx.x] = h[i];  // scattered store (fire-and-forget)
}

// ---- phase 2a: per-bin scan, COALESCED hist[bin][t] loads ----
__global__ __launch_bounds__(512) void k_scan_a(const int* __restrict__ hist,
                                                int* __restrict__ partial,
                                                int* __restrict__ gtot) {
  __shared__ int sv[512];
  int bin = blockIdx.x, t = threadIdx.x;
  int v = (t < NB) ? hist[bin * NB + t] : 0;
  sv[t] = v;
  __syncthreads();
  for (int o = 1; o < 512; o <<= 1) {
    int a = (t >= o) ? sv[t - o] : 0;
    __syncthreads();
    sv[t] += a;
    __syncthreads();
  }
  if (t < NB) partial[t * NBIN + bin] = sv[t] - v;
  if (t == 511) gtot[bin] = sv[511];
}

// ---- phase 2b: exclusive scan of the 400 bin totals -> segment bases ----
__global__ __launch_bounds__(512) void k_scan_b(const int* __restrict__ gtot,
                                                int* __restrict__ gbase) {
  __shared__ int sv[512];
  int t = threadIdx.x;
  int v = (t < NBIN) ? gtot[t] : 0;
  sv[t] = v;
  __syncthreads();
  for (int o = 1; o < 512; o <<= 1) {
    int a = (t >= o) ? sv[t - o] : 0;
    __syncthreads();
    sv[t] += a;
    __syncthreads();
  }
  if (t < NBIN) gbase[t] = sv[t] - v;
  if (t == 511) gbase[NBIN] = sv[511];
}

// ---- phase 3: scatter edges into bin segments (LDS cursors, 1x 8B store) ----
__global__ __launch_bounds__(256) void k_bfill(const int* __restrict__ ei,
                                               const int* __restrict__ partial,
                                               const int* __restrict__ gbase,
                                               unsigned long long* __restrict__ ebuf) {
  __shared__ int cur[NBIN];
  int b = blockIdx.x;
  for (int i = threadIdx.x; i < NBIN; i += 256)
    cur[i] = gbase[i] + partial[b * NBIN + i];
  __syncthreads();
  int e0 = b * ECH;
  for (int i = threadIdx.x; i < ECH; i += 256) {
    int e = e0 + i;
    int d = ei[NE + e], s = ei[e];
    int bin = d / 250;
    int gb = (bin >> 2) * 1000;
    unsigned long long pk = (unsigned long long)(unsigned)e << 32 |
                            (unsigned)((d - gb) << 10) | (unsigned)(s - gb);
    int pos = atomicAdd(&cur[bin], 1);
    ebuf[pos] = pk;
  }
}

// ---- phase 4: within-bin counting sort by node -> per-node CSR (1024 thr) ----
__global__ __launch_bounds__(1024) void k_nsort(
    const unsigned long long* __restrict__ ebuf, const int* __restrict__ gbase,
    unsigned* __restrict__ ebuf2, int* __restrict__ rowptr,
    int* __restrict__ cnt) {
  __shared__ int h[250];
  __shared__ int cur[250];
  __shared__ int sv[256];
  int bin = blockIdx.x, t = threadIdx.x;
  int nb = bin * 250, lbase = (bin & 3) * 250;
  int lo = gbase[bin], hi = gbase[bin + 1];
  if (t < 250) h[t] = 0;
  __syncthreads();
  for (int i = lo + t; i < hi; i += 1024) {
    int dl = (int)((ebuf[i] >> 10) & 1023);
    atomicAdd(&h[dl - lbase], 1);
  }
  __syncthreads();
  int v = (t < 250) ? h[t] : 0;
  if (t < 256) sv[t] = v;
  __syncthreads();
  for (int o = 1; o < 256; o <<= 1) {
    int a = (t < 256 && t >= o) ? sv[t - o] : 0;
    __syncthreads();
    if (t < 256) sv[t] += a;
    __syncthreads();
  }
  if (t < 250) {
    int base = lo + sv[t] - v;  // exclusive
    rowptr[nb + t] = base;
    cur[t] = base;
    cnt[nb + t] = v;
  }
  if (bin == NBIN - 1 && t == 0) rowptr[NN] = hi;
  __syncthreads();
  for (int i = lo + t; i < hi; i += 1024) {
    unsigned long long u = ebuf[i];
    int dl = (int)((u >> 10) & 1023);
    unsigned pk = (unsigned)(u >> 32) << 10 | (unsigned)(u & 1023);
    int pos = atomicAdd(&cur[dl - lbase], 1);
    ebuf2[pos] = pk;
  }
}

// ---- Se: wave-per-node float4 gather (R10 shape); PACKED BF16 [n][16] ----
#define SEB 25000
__global__ __launch_bounds__(256) void k_se3(const unsigned* __restrict__ ebuf2,
                                             const int* __restrict__ rowptr,
                                             const float* __restrict__ ea,
                                             ushort* __restrict__ Se16) {
  int lane = threadIdx.x & 63;
  int slot = lane >> 2;  // edge slot 0..15
  int q = lane & 3;      // row quarter (4 channels)
  int orig = blockIdx.x;
  int blk = (orig & 7) * (SEB / 8) + (orig >> 3);
  int n0 = blk * 4 + (threadIdx.x >> 6);
  if (n0 >= NN) return;
  int n = __builtin_amdgcn_readfirstlane(n0);
  int lo = rowptr[n], hi = rowptr[n + 1];
  float aA0 = 0.f, aA1 = 0.f, aA2 = 0.f, aA3 = 0.f;
  float aB0 = 0.f, aB1 = 0.f, aB2 = 0.f, aB3 = 0.f;
  for (int k0 = lo; k0 < hi; k0 += 32) {
    int ka = k0 + slot, kb = k0 + 16 + slot;
    int kca = min(ka, NE - 1), kcb = min(kb, NE - 1);
    unsigned eida = ebuf2[kca] >> 10;
    unsigned eidb = ebuf2[kcb] >> 10;
    float4 va = *(const float4*)(ea + (size_t)eida * CE + q * 4);
    float4 vb = *(const float4*)(ea + (size_t)eidb * CE + q * 4);
    bool oka = ka < hi, okb = kb < hi;
    aA0 += oka ? va.x : 0.f;
    aA1 += oka ? va.y : 0.f;
    aA2 += oka ? va.z : 0.f;
    aA3 += oka ? va.w : 0.f;
    aB0 += okb ? vb.x : 0.f;
    aB1 += okb ? vb.y : 0.f;
    aB2 += okb ? vb.z : 0.f;
    aB3 += okb ? vb.w : 0.f;
  }
  float r0 = aA0 + aB0, r1 = aA1 + aB1, r2 = aA2 + aB2, r3 = aA3 + aB3;
#pragma unroll
  for (int o = 4; o < 64; o <<= 1) {
    r0 += __shfl_xor(r0, o);
    r1 += __shfl_xor(r1, o);
    r2 += __shfl_xor(r2, o);
    r3 += __shfl_xor(r3, o);
  }
  if (lane < 4) {
    unsigned lo32 = (unsigned)f2bf_rne(r0) | ((unsigned)f2bf_rne(r1) << 16);
    unsigned hi32 = (unsigned)f2bf_rne(r2) | ((unsigned)f2bf_rne(r3) << 16);
    *(uint2*)(Se16 + (size_t)n * 16 + lane * 4) = make_uint2(lo32, hi32);
  }
}

// ---------------- per-layer node GEMM via MFMA (R12; templated) ------------
#define GEMM_TILES (NN / 16)  // 6250
#define GB 512
template <typename T>
__global__ __attribute__((amdgpu_waves_per_eu(2, 4))) __launch_bounds__(256)
void k_gemm(const T* __restrict__ x, const float* __restrict__ W,
            const float* __restrict__ b, const int* __restrict__ cnt,
            const ushort* __restrict__ Se16, ushort* __restrict__ y,
            ushort* __restrict__ z) {
  int lane = threadIdx.x & 63;
  int g = lane >> 4, r16 = lane & 15;

  ABu Bm[8][2];
  ABu Bs[4];
  float bias4[4];
#pragma unroll
  for (int t = 0; t < 8; ++t) {
    int col = t * 16 + r16;
    const float* wbase = W + (col < 64 ? 0 : 64 * 64);
    int c64 = col & 63;
#pragma unroll
    for (int h = 0; h < 2; ++h)
#pragma unroll
      for (int e = 0; e < 8; ++e) {
        int k = h * 32 + (e < 4 ? 0 : 16) + 4 * g + (e & 3);
        Bm[t][h].u[e] = f2bf_rne(wbase[k * 64 + c64]);
      }
  }
#pragma unroll
  for (int t = 0; t < 4; ++t) {
    int col = t * 16 + r16;
    float ws = 0.f;
#pragma unroll
    for (int m = 0; m < 16; ++m) ws += W[(128 + m) * 64 + col];
#pragma unroll
    for (int e = 0; e < 8; ++e) {
      int k = (e < 4 ? 0 : 16) + 4 * g + (e & 3);
      float v = (k < 16) ? W[(128 + k) * 64 + col] : (k == 16 ? ws : 0.f);
      Bs[t].u[e] = f2bf_rne(v);
    }
    bias4[t] = b[col];
  }

  int wid = (blockIdx.x << 2) + (threadIdx.x >> 6);
  int nw = GB * 4;
  for (int tt = wid; tt < GEMM_TILES; tt += nw) {
    int nb = tt * 16;
    ABu A0, A1, AS;
    if constexpr (sizeof(T) == 4) {
      const float* xr = (const float*)x + (size_t)(nb + r16) * HH;
      float4 f0 = *(const float4*)(xr + 4 * g);
      float4 f1 = *(const float4*)(xr + 16 + 4 * g);
      float4 f2 = *(const float4*)(xr + 32 + 4 * g);
      float4 f3 = *(const float4*)(xr + 48 + 4 * g);
      A0.u[0] = f2bf_rne(f0.x); A0.u[1] = f2bf_rne(f0.y);
      A0.u[2] = f2bf_rne(f0.z); A0.u[3] = f2bf_rne(f0.w);
      A0.u[4] = f2bf_rne(f1.x); A0.u[5] = f2bf_rne(f1.y);
      A0.u[6] = f2bf_rne(f1.z); A0.u[7] = f2bf_rne(f1.w);
      A1.u[0] = f2bf_rne(f2.x); A1.u[1] = f2bf_rne(f2.y);
      A1.u[2] = f2bf_rne(f2.z); A1.u[3] = f2bf_rne(f2.w);
      A1.u[4] = f2bf_rne(f3.x); A1.u[5] = f2bf_rne(f3.y);
      A1.u[6] = f2bf_rne(f3.z); A1.u[7] = f2bf_rne(f3.w);
    } else {
      const ushort* xr = (const ushort*)x + (size_t)(nb + r16) * HH;
      *(ushort4*)&A0.u[0] = *(const ushort4*)(xr + 4 * g);
      *(ushort4*)&A0.u[4] = *(const ushort4*)(xr + 16 + 4 * g);
      *(ushort4*)&A1.u[0] = *(const ushort4*)(xr + 32 + 4 * g);
      *(ushort4*)&A1.u[4] = *(const ushort4*)(xr + 48 + 4 * g);
    }
    const ushort* sr = Se16 + (size_t)(nb + r16) * 16;
    *(ushort4*)&AS.u[0] = *(const ushort4*)(sr + 4 * g);
    AS.u[4] = (g == 0) ? (ushort)0x3F80 : (ushort)0;  // k==16 -> 1.0
    AS.u[5] = 0; AS.u[6] = 0; AS.u[7] = 0;
    float dq[4];
#pragma unroll
    for (int q = 0; q < 4; ++q) dq[q] = (float)(cnt[nb + 4 * g + q] + 1);

    f32x4 accM[8], accS[4];
#pragma unroll
    for (int t = 0; t < 8; ++t) {
      f32x4 zz = {0.f, 0.f, 0.f, 0.f};
      zz = __builtin_amdgcn_mfma_f32_16x16x32_bf16(A0.f, Bm[t][0].f, zz, 0, 0, 0);
      accM[t] = __builtin_amdgcn_mfma_f32_16x16x32_bf16(A1.f, Bm[t][1].f, zz, 0, 0, 0);
    }
#pragma unroll
    for (int t = 0; t < 4; ++t) {
      f32x4 zz = {0.f, 0.f, 0.f, 0.f};
      accS[t] = __builtin_amdgcn_mfma_f32_16x16x32_bf16(AS.f, Bs[t].f, zz, 0, 0, 0);
    }
#pragma unroll
    for (int q = 0; q < 4; ++q) {
      size_t node = (size_t)(nb + 4 * g + q);
      ushort* zp = z + node * 64 + r16;
      ushort* yp = y + node * 64 + r16;
#pragma unroll
      for (int t = 0; t < 4; ++t) {
        float zv = dq[q] * (accM[t][q] + bias4[t]) + accS[t][q];
        zp[t * 16] = f2bf_rne(zv);
        yp[t * 16] = f2bf_rne(accM[4 + t][q]);
      }
    }
  }
}

// ---- per-layer gather: R13 EXACT (wave-per-node, 8-deep ILP + serial tail) ----
#define GTB 25000
__global__ __launch_bounds__(256) void k_gath3(
    const __hip_bfloat16* __restrict__ y, const __hip_bfloat16* __restrict__ z,
    const unsigned* __restrict__ ebuf2, const int* __restrict__ rowptr,
    const float* __restrict__ gamma, const float* __restrict__ beta,
    __hip_bfloat16* __restrict__ xn, float* __restrict__ emb) {
  int lane = threadIdx.x & 63;
  int orig = blockIdx.x;
  int blk = (orig & 7) * (GTB / 8) + (orig >> 3);
  int n0 = blk * 4 + (threadIdx.x >> 6);
  if (n0 >= NN) return;
  int n = __builtin_amdgcn_readfirstlane(n0);
  int lo = rowptr[n], hi = rowptr[n + 1];
  int deg = hi - lo;
  int gb = (n / NPG) * NPG;
  const unsigned* cl = ebuf2 + lo;
  const __hip_bfloat16* yg = y + (size_t)gb * HH;
  float acc = __bfloat162float(z[(size_t)n * HH + lane]) +
              __bfloat162float(y[(size_t)n * HH + lane]);
  int k = 0;
  for (; k + 8 <= deg; k += 8) {
    int s0 = cl[k] & 1023, s1 = cl[k + 1] & 1023;
    int s2 = cl[k + 2] & 1023, s3 = cl[k + 3] & 1023;
    int s4 = cl[k + 4] & 1023, s5 = cl[k + 5] & 1023;
    int s6 = cl[k + 6] & 1023, s7 = cl[k + 7] & 1023;
    float v0 = __bfloat162float(yg[(size_t)s0 * HH + lane]);
    float v1 = __bfloat162float(yg[(size_t)s1 * HH + lane]);
    float v2 = __bfloat162float(yg[(size_t)s2 * HH + lane]);
    float v3 = __bfloat162float(yg[(size_t)s3 * HH + lane]);
    float v4 = __bfloat162float(yg[(size_t)s4 * HH + lane]);
    float v5 = __bfloat162float(yg[(size_t)s5 * HH + lane]);
    float v6 = __bfloat162float(yg[(size_t)s6 * HH + lane]);
    float v7 = __bfloat162float(yg[(size_t)s7 * HH + lane]);
    acc += ((v0 + v1) + (v2 + v3)) + ((v4 + v5) + (v6 + v7));
  }
  for (; k < deg; ++k)
    acc += __bfloat162float(yg[(size_t)(cl[k] & 1023) * HH + lane]);
  acc = fmaxf(acc, 0.f);
  acc = gamma[lane] * acc * BN_SCALE + beta[lane];
  acc = fmaxf(acc, 0.f);
  xn[(size_t)n * HH + lane] = __float2bfloat16(acc);
  if (n % NPG == 0) emb[(n / NPG) * HH + lane] = acc;
}

// ---- readout: FUSED pool + MLP (1024 threads: 16-wave pooling, 4-way fc1) ----
__global__ __launch_bounds__(1024) void k_final(
    const __hip_bfloat16* __restrict__ xf, const float* __restrict__ emb,
    const float* __restrict__ nbr, const float* __restrict__ fc1w,
    const float* __restrict__ fc1b, const float* __restrict__ fc2w,
    const float* __restrict__ fc2b, float* __restrict__ out) {
  __shared__ float pp[16][64];
  __shared__ float feats[320];
  __shared__ float r1p[4][256];
  __shared__ float red[4][4];
  int g = blockIdx.x;
  int t = threadIdx.x;
  int lane = t & 63, wv = t >> 6;
  const __hip_bfloat16* base = xf + (size_t)g * NPG * HH;
  float acc = 0.f;
  int i = wv;
  for (; i + 48 < NPG; i += 64) {
    float v0 = __bfloat162float(base[(size_t)i * HH + lane]);
    float v1 = __bfloat162float(base[(size_t)(i + 16) * HH + lane]);
    float v2 = __bfloat162float(base[(size_t)(i + 32) * HH + lane]);
    float v3 = __bfloat162float(base[(size_t)(i + 48) * HH + lane]);
    acc += (v0 + v1) + (v2 + v3);
  }
  for (; i < NPG; i += 16) acc += __bfloat162float(base[(size_t)i * HH + lane]);
  pp[wv][lane] = acc;
  __syncthreads();
  if (t < 64) {
    float s = 0.f;
#pragma unroll
    for (int w = 0; w < 16; ++w) s += pp[w][t];
    feats[t] = s;
    feats[256 + t] = nbr[(size_t)g * HH + t];
  } else if (t < 256) {
    int j = t - 64;
    feats[64 + j] = emb[((size_t)(j >> 6) * NG + g) * HH + (j & 63)];
  } else if (t < 384) {
    int j = t - 256 + 128;  // embs 128..255
    feats[64 + j] = emb[((size_t)(j >> 6) * NG + g) * HH + (j & 63)];
  }
  __syncthreads();
  int o = t & 255, tg = t >> 8;
  float a0 = 0.f, a1 = 0.f, a2 = 0.f, a3 = 0.f;
  const float* wp = fc1w + o;
  for (int k = tg * 80; k < tg * 80 + 80; k += 8) {
    float w0 = wp[(k + 0) * 256], w1 = wp[(k + 1) * 256];
    float w2 = wp[(k + 2) * 256], w3 = wp[(k + 3) * 256];
    float w4 = wp[(k + 4) * 256], w5 = wp[(k + 5) * 256];
    float w6 = wp[(k + 6) * 256], w7 = wp[(k + 7) * 256];
    a0 = fmaf(feats[k], w0, a0);
    a1 = fmaf(feats[k + 1], w1, a1);
    a2 = fmaf(feats[k + 2], w2, a2);
    a3 = fmaf(feats[k + 3], w3, a3);
    a0 = fmaf(feats[k + 4], w4, a0);
    a1 = fmaf(feats[k + 5], w5, a1);
    a2 = fmaf(feats[k + 6], w6, a2);
    a3 = fmaf(feats[k + 7], w7, a3);
  }
  r1p[tg][o] = (a0 + a1) + (a2 + a3);
  __syncthreads();
  if (t < 256) {
    float rv = fmaxf(fc1b[t] + ((r1p[0][t] + r1p[1][t]) + (r1p[2][t] + r1p[3][t])),
                     0.f);
    float p0 = rv * fc2w[t * 4 + 0];
    float p1 = rv * fc2w[t * 4 + 1];
    float p2 = rv * fc2w[t * 4 + 2];
    float p3 = rv * fc2w[t * 4 + 3];
#pragma unroll
    for (int oo = 1; oo < 64; oo <<= 1) {
      p0 += __shfl_xor(p0, oo);
      p1 += __shfl_xor(p1, oo);
      p2 += __shfl_xor(p2, oo);
      p3 += __shfl_xor(p3, oo);
    }
    if ((t & 63) == 0) {
      red[t >> 6][0] = p0; red[t >> 6][1] = p1;
      red[t >> 6][2] = p2; red[t >> 6][3] = p3;
    }
  }
  __syncthreads();
  if (t < 4)
    out[g * 4 + t] = fc2b[t] +
                     ((red[0][t] + red[1][t]) + (red[2][t] + red[3][t]));
}

extern "C" void kernel_launch(void* const* d_in, const int* in_sizes, int n_in,
                              void* d_out, int out_size, void* d_ws, size_t ws_size,
                              hipStream_t stream) {
  const float* x     = (const float*)d_in[0];
  const float* eattr = (const float*)d_in[1];
  const float* nbr   = (const float*)d_in[2];
  const float* W     = (const float*)d_in[3];
  const float* b     = (const float*)d_in[4];
  const float* gamma = (const float*)d_in[5];
  const float* beta  = (const float*)d_in[6];
  const float* fc1w  = (const float*)d_in[7];
  const float* fc1b  = (const float*)d_in[8];
  const float* fc2w  = (const float*)d_in[9];
  const float* fc2b  = (const float*)d_in[10];
  const int*   ei    = (const int*)d_in[11];
  float* out = (float*)d_out;
  (void)in_sizes; (void)n_in; (void)out_size; (void)ws_size;

  char* p = (char*)d_ws;
  size_t off = 0;
  auto alloc = [&](size_t bytes) {
    char* q = p + off;
    off += (bytes + 255) & ~(size_t)255;
    return q;
  };
  int* hist    = (int*)alloc((size_t)NB * NBIN * 4);  // [NBIN][NB] transposed
  int* partial = (int*)alloc((size_t)NB * NBIN * 4);
  int* gtot    = (int*)alloc((size_t)NBIN * 4);
  int* gbase   = (int*)alloc((size_t)(NBIN + 1) * 4);
  unsigned long long* ebuf = (unsigned long long*)alloc((size_t)NE * 8);
  unsigned* ebuf2 = (unsigned*)alloc((size_t)NE * 4);
  int* rowptr  = (int*)alloc((size_t)(NN + 1) * 4);
  ushort* Se16 = (ushort*)alloc((size_t)NN * 16 * 2);
  int*   cnt   = (int*)alloc((size_t)NN * 4);
  ushort* ybuf = (ushort*)alloc((size_t)NN * HH * 2);
  ushort* zbuf = (ushort*)alloc((size_t)NN * HH * 2);
  ushort* xA   = (ushort*)alloc((size_t)NN * HH * 2);
  ushort* xB   = (ushort*)alloc((size_t)NN * HH * 2);
  float* emb   = (float*)alloc((size_t)3 * NG * HH * 4);

  // CSR build via two-level counting sort (zero global f32 atomics, no fences)
  k_hist<<<NB, 256, 0, stream>>>(ei, hist);
  k_scan_a<<<NBIN, 512, 0, stream>>>(hist, partial, gtot);
  k_scan_b<<<1, 512, 0, stream>>>(gtot, gbase);
  k_bfill<<<NB, 256, 0, stream>>>(ei, partial, gbase, ebuf);
  k_nsort<<<NBIN, 1024, 0, stream>>>(ebuf, gbase, ebuf2, rowptr, cnt);
  k_se3<<<SEB, 256, 0, stream>>>(ebuf2, rowptr, eattr, Se16);

  // layer 0: x (f32) -> xA
  k_gemm<float><<<GB, 256, 0, stream>>>(x, W, b, cnt, Se16, ybuf, zbuf);
  k_gath3<<<GTB, 256, 0, stream>>>((const __hip_bfloat16*)ybuf,
                                   (const __hip_bfloat16*)zbuf, ebuf2, rowptr,
                                   gamma, beta, (__hip_bfloat16*)xA, emb);
  // layer 1: xA -> xB
  k_gemm<ushort><<<GB, 256, 0, stream>>>(xA, W + 144 * 64, b + 64, cnt, Se16,
                                         ybuf, zbuf);
  k_gath3<<<GTB, 256, 0, stream>>>((const __hip_bfloat16*)ybuf,
                                   (const __hip_bfloat16*)zbuf, ebuf2, rowptr,
                                   gamma + 64, beta + 64, (__hip_bfloat16*)xB,
                                   emb + NG * HH);
  // layer 2: xB -> xA
  k_gemm<ushort><<<GB, 256, 0, stream>>>(xB, W + 2 * 144 * 64, b + 128, cnt,
                                         Se16, ybuf, zbuf);
  k_gath3<<<GTB, 256, 0, stream>>>((const __hip_bfloat16*)ybuf,
                                   (const __hip_bfloat16*)zbuf, ebuf2, rowptr,
                                   gamma + 128, beta + 128, (__hip_bfloat16*)xA,
                                   emb + 2 * NG * HH);

  k_final<<<NG, 1024, 0, stream>>>((const __hip_bfloat16*)xA, emb, nbr, fc1w,
                                   fc1b, fc2w, fc2b, out);
}

// Round 20
// 246.407 us; speedup vs baseline: 1.8674x; 1.0246x over previous
//
#include <hip/hip_runtime.h>
#include <hip/hip_bf16.h>

#define NN 100000   // nodes
#define NE 1600000  // edges
#define NG 100      // graphs
#define NPG 1000    // nodes per graph
#define CE 16       // edge channels
#define HH 64       // hidden
#define BN_SCALE 0.99999500003749959f  // 1/sqrt(1+1e-5)
#define NB 512          // edge-chunk blocks
#define ECH (NE / NB)   // 3125 edges per chunk
#define NBIN 400        // dst bins: bin = dst/250 (4 bins per graph)

// LESSON (R3): f32 global atomicAdd on gfx950 = near-memory RMW (~35B HBM each).
// LESSON (R5): int global atomics ~40B each -> counting-sort CSR, no atomics.
// LESSON (R6/R16): per-edge work must be SPREAD ACROSS LANES; serial per-thread
// chains (16 LDS atomics, or one-edge-per-wave-instr) serialize ~10x.
// LESSON (R8): W "register cache" via LDS stays in LDS; use global loads.
// LESSON (R9): un-unrolled load+add loops serialize at L2/L3 latency.
// LESSON (R10): guarded loads serialize when occupancy is LOW; clamp+cndmask.
// LESSON (R11/R12): allocator targets 84 VGPR; s_load returns out-of-order.
// Node GEMMs belong on MFMA.
// LESSON (R13): give every build phase >=2k waves.
// LESSON (R14): wave-uniform scalar index loads are nearly free.
// LESSON (R15): at HIGH occupancy TLP hides serial tails.
// LESSON (R17): per-block __threadfence() x400 = 90us. Strided LOADS stall,
// strided STORES don't: scatter on the producer, coalesce the consumer.
// LESSON (R19): keep producer/consumer on the SAME XCD node ranges across the
// whole chain (gemm writes y/z where gath reads them) — R12 dropped this.

typedef __attribute__((ext_vector_type(8))) short bf16x8;
typedef __attribute__((ext_vector_type(4))) float f32x4;
union ABu { bf16x8 f; ushort u[8]; };

__device__ __forceinline__ ushort f2bf_rne(float f) {
  unsigned u = __float_as_uint(f);
  return (ushort)((u + 0x7FFFu + ((u >> 16) & 1u)) >> 16);
}

// ---- phase 1: per-chunk histogram; TRANSPOSED store hist[bin][chunk] ----
__global__ __launch_bounds__(256) void k_hist(const int* __restrict__ ei,
                                              int* __restrict__ hist) {
  __shared__ int h[NBIN];
  for (int i = threadIdx.x; i < NBIN; i += 256) h[i] = 0;
  __syncthreads();
  int e0 = blockIdx.x * ECH;
  for (int i = threadIdx.x; i < ECH; i += 256) {
    int d = ei[NE + e0 + i];
    atomicAdd(&h[d / 250], 1);
  }
  __syncthreads();
  for (int i = threadIdx.x; i < NBIN; i += 256)
    hist[i * NB + blockIdx.x] = h[i];  // scattered store (fire-and-forget)
}

// ---- phase 2a: per-bin scan, COALESCED hist[bin][t] loads ----
__global__ __launch_bounds__(512) void k_scan_a(const int* __restrict__ hist,
                                                int* __restrict__ partial,
                                                int* __restrict__ gtot) {
  __shared__ int sv[512];
  int bin = blockIdx.x, t = threadIdx.x;
  int v = (t < NB) ? hist[bin * NB + t] : 0;
  sv[t] = v;
  __syncthreads();
  for (int o = 1; o < 512; o <<= 1) {
    int a = (t >= o) ? sv[t - o] : 0;
    __syncthreads();
    sv[t] += a;
    __syncthreads();
  }
  if (t < NB) partial[t * NBIN + bin] = sv[t] - v;
  if (t == 511) gtot[bin] = sv[511];
}

// ---- phase 2b: exclusive scan of the 400 bin totals -> segment bases ----
__global__ __launch_bounds__(512) void k_scan_b(const int* __restrict__ gtot,
                                                int* __restrict__ gbase) {
  __shared__ int sv[512];
  int t = threadIdx.x;
  int v = (t < NBIN) ? gtot[t] : 0;
  sv[t] = v;
  __syncthreads();
  for (int o = 1; o < 512; o <<= 1) {
    int a = (t >= o) ? sv[t - o] : 0;
    __syncthreads();
    sv[t] += a;
    __syncthreads();
  }
  if (t < NBIN) gbase[t] = sv[t] - v;
  if (t == 511) gbase[NBIN] = sv[511];
}

// ---- phase 3: scatter edges into bin segments (LDS cursors, 1x 8B store) ----
__global__ __launch_bounds__(256) void k_bfill(const int* __restrict__ ei,
                                               const int* __restrict__ partial,
                                               const int* __restrict__ gbase,
                                               unsigned long long* __restrict__ ebuf) {
  __shared__ int cur[NBIN];
  int b = blockIdx.x;
  for (int i = threadIdx.x; i < NBIN; i += 256)
    cur[i] = gbase[i] + partial[b * NBIN + i];
  __syncthreads();
  int e0 = b * ECH;
  for (int i = threadIdx.x; i < ECH; i += 256) {
    int e = e0 + i;
    int d = ei[NE + e], s = ei[e];
    int bin = d / 250;
    int gb = (bin >> 2) * 1000;
    unsigned long long pk = (unsigned long long)(unsigned)e << 32 |
                            (unsigned)((d - gb) << 10) | (unsigned)(s - gb);
    int pos = atomicAdd(&cur[bin], 1);
    ebuf[pos] = pk;
  }
}

// ---- phase 4: within-bin counting sort by node -> per-node CSR (1024 thr) ----
__global__ __launch_bounds__(1024) void k_nsort(
    const unsigned long long* __restrict__ ebuf, const int* __restrict__ gbase,
    unsigned* __restrict__ ebuf2, int* __restrict__ rowptr,
    int* __restrict__ cnt) {
  __shared__ int h[250];
  __shared__ int cur[250];
  __shared__ int sv[256];
  int bin = blockIdx.x, t = threadIdx.x;
  int nb = bin * 250, lbase = (bin & 3) * 250;
  int lo = gbase[bin], hi = gbase[bin + 1];
  if (t < 250) h[t] = 0;
  __syncthreads();
  for (int i = lo + t; i < hi; i += 1024) {
    int dl = (int)((ebuf[i] >> 10) & 1023);
    atomicAdd(&h[dl - lbase], 1);
  }
  __syncthreads();
  int v = (t < 250) ? h[t] : 0;
  if (t < 256) sv[t] = v;
  __syncthreads();
  for (int o = 1; o < 256; o <<= 1) {
    int a = (t < 256 && t >= o) ? sv[t - o] : 0;
    __syncthreads();
    if (t < 256) sv[t] += a;
    __syncthreads();
  }
  if (t < 250) {
    int base = lo + sv[t] - v;  // exclusive
    rowptr[nb + t] = base;
    cur[t] = base;
    cnt[nb + t] = v;
  }
  if (bin == NBIN - 1 && t == 0) rowptr[NN] = hi;
  __syncthreads();
  for (int i = lo + t; i < hi; i += 1024) {
    unsigned long long u = ebuf[i];
    int dl = (int)((u >> 10) & 1023);
    unsigned pk = (unsigned)(u >> 32) << 10 | (unsigned)(u & 1023);
    int pos = atomicAdd(&cur[dl - lbase], 1);
    ebuf2[pos] = pk;
  }
}

// ---- Se: wave-per-node float4 gather (R10 shape); PACKED BF16 [n][16] ----
#define SEB 25000
__global__ __launch_bounds__(256) void k_se3(const unsigned* __restrict__ ebuf2,
                                             const int* __restrict__ rowptr,
                                             const float* __restrict__ ea,
                                             ushort* __restrict__ Se16) {
  int lane = threadIdx.x & 63;
  int slot = lane >> 2;  // edge slot 0..15
  int q = lane & 3;      // row quarter (4 channels)
  int orig = blockIdx.x;
  int blk = (orig & 7) * (SEB / 8) + (orig >> 3);
  int n0 = blk * 4 + (threadIdx.x >> 6);
  if (n0 >= NN) return;
  int n = __builtin_amdgcn_readfirstlane(n0);
  int lo = rowptr[n], hi = rowptr[n + 1];
  float aA0 = 0.f, aA1 = 0.f, aA2 = 0.f, aA3 = 0.f;
  float aB0 = 0.f, aB1 = 0.f, aB2 = 0.f, aB3 = 0.f;
  for (int k0 = lo; k0 < hi; k0 += 32) {
    int ka = k0 + slot, kb = k0 + 16 + slot;
    int kca = min(ka, NE - 1), kcb = min(kb, NE - 1);
    unsigned eida = ebuf2[kca] >> 10;
    unsigned eidb = ebuf2[kcb] >> 10;
    float4 va = *(const float4*)(ea + (size_t)eida * CE + q * 4);
    float4 vb = *(const float4*)(ea + (size_t)eidb * CE + q * 4);
    bool oka = ka < hi, okb = kb < hi;
    aA0 += oka ? va.x : 0.f;
    aA1 += oka ? va.y : 0.f;
    aA2 += oka ? va.z : 0.f;
    aA3 += oka ? va.w : 0.f;
    aB0 += okb ? vb.x : 0.f;
    aB1 += okb ? vb.y : 0.f;
    aB2 += okb ? vb.z : 0.f;
    aB3 += okb ? vb.w : 0.f;
  }
  float r0 = aA0 + aB0, r1 = aA1 + aB1, r2 = aA2 + aB2, r3 = aA3 + aB3;
#pragma unroll
  for (int o = 4; o < 64; o <<= 1) {
    r0 += __shfl_xor(r0, o);
    r1 += __shfl_xor(r1, o);
    r2 += __shfl_xor(r2, o);
    r3 += __shfl_xor(r3, o);
  }
  if (lane < 4) {
    unsigned lo32 = (unsigned)f2bf_rne(r0) | ((unsigned)f2bf_rne(r1) << 16);
    unsigned hi32 = (unsigned)f2bf_rne(r2) | ((unsigned)f2bf_rne(r3) << 16);
    *(uint2*)(Se16 + (size_t)n * 16 + lane * 4) = make_uint2(lo32, hi32);
  }
}

// ------- per-layer node GEMM via MFMA; XCD-range tile mapping (R19) --------
#define GEMM_TILES (NN / 16)  // 6250
#define TPX 782               // tiles per XCD (ceil 6250/8)
#define GB 512                // 64 blocks -> 256 waves per XCD
template <typename T>
__global__ __attribute__((amdgpu_waves_per_eu(2, 4))) __launch_bounds__(256)
void k_gemm(const T* __restrict__ x, const float* __restrict__ W,
            const float* __restrict__ b, const int* __restrict__ cnt,
            const ushort* __restrict__ Se16, ushort* __restrict__ y,
            ushort* __restrict__ z) {
  int lane = threadIdx.x & 63;
  int g = lane >> 4, r16 = lane & 15;

  ABu Bm[8][2];
  ABu Bs[4];
  float bias4[4];
#pragma unroll
  for (int t = 0; t < 8; ++t) {
    int col = t * 16 + r16;
    const float* wbase = W + (col < 64 ? 0 : 64 * 64);
    int c64 = col & 63;
#pragma unroll
    for (int h = 0; h < 2; ++h)
#pragma unroll
      for (int e = 0; e < 8; ++e) {
        int k = h * 32 + (e < 4 ? 0 : 16) + 4 * g + (e & 3);
        Bm[t][h].u[e] = f2bf_rne(wbase[k * 64 + c64]);
      }
  }
#pragma unroll
  for (int t = 0; t < 4; ++t) {
    int col = t * 16 + r16;
    float ws = 0.f;
#pragma unroll
    for (int m = 0; m < 16; ++m) ws += W[(128 + m) * 64 + col];
#pragma unroll
    for (int e = 0; e < 8; ++e) {
      int k = (e < 4 ? 0 : 16) + 4 * g + (e & 3);
      float v = (k < 16) ? W[(128 + k) * 64 + col] : (k == 16 ? ws : 0.f);
      Bs[t].u[e] = f2bf_rne(v);
    }
    bias4[t] = b[col];
  }

  // XCD-range tile mapping: XCD i owns tiles [i*TPX, (i+1)*TPX) -> its y/z
  // writes land in the L2 that k_gath3 (same node ranges) reads from.
  int xcd = blockIdx.x & 7;
  int wid = (blockIdx.x >> 3) * 4 + (threadIdx.x >> 6);  // 0..255 within XCD
  int tend = min((xcd + 1) * TPX, GEMM_TILES);
  for (int tt = xcd * TPX + wid; tt < tend; tt += (GB / 8) * 4) {
    int nb = tt * 16;
    ABu A0, A1, AS;
    if constexpr (sizeof(T) == 4) {
      const float* xr = (const float*)x + (size_t)(nb + r16) * HH;
      float4 f0 = *(const float4*)(xr + 4 * g);
      float4 f1 = *(const float4*)(xr + 16 + 4 * g);
      float4 f2 = *(const float4*)(xr + 32 + 4 * g);
      float4 f3 = *(const float4*)(xr + 48 + 4 * g);
      A0.u[0] = f2bf_rne(f0.x); A0.u[1] = f2bf_rne(f0.y);
      A0.u[2] = f2bf_rne(f0.z); A0.u[3] = f2bf_rne(f0.w);
      A0.u[4] = f2bf_rne(f1.x); A0.u[5] = f2bf_rne(f1.y);
      A0.u[6] = f2bf_rne(f1.z); A0.u[7] = f2bf_rne(f1.w);
      A1.u[0] = f2bf_rne(f2.x); A1.u[1] = f2bf_rne(f2.y);
      A1.u[2] = f2bf_rne(f2.z); A1.u[3] = f2bf_rne(f2.w);
      A1.u[4] = f2bf_rne(f3.x); A1.u[5] = f2bf_rne(f3.y);
      A1.u[6] = f2bf_rne(f3.z); A1.u[7] = f2bf_rne(f3.w);
    } else {
      const ushort* xr = (const ushort*)x + (size_t)(nb + r16) * HH;
      *(ushort4*)&A0.u[0] = *(const ushort4*)(xr + 4 * g);
      *(ushort4*)&A0.u[4] = *(const ushort4*)(xr + 16 + 4 * g);
      *(ushort4*)&A1.u[0] = *(const ushort4*)(xr + 32 + 4 * g);
      *(ushort4*)&A1.u[4] = *(const ushort4*)(xr + 48 + 4 * g);
    }
    const ushort* sr = Se16 + (size_t)(nb + r16) * 16;
    *(ushort4*)&AS.u[0] = *(const ushort4*)(sr + 4 * g);
    AS.u[4] = (g == 0) ? (ushort)0x3F80 : (ushort)0;  // k==16 -> 1.0
    AS.u[5] = 0; AS.u[6] = 0; AS.u[7] = 0;
    float dq[4];
#pragma unroll
    for (int q = 0; q < 4; ++q) dq[q] = (float)(cnt[nb + 4 * g + q] + 1);

    f32x4 accM[8], accS[4];
#pragma unroll
    for (int t = 0; t < 8; ++t) {
      f32x4 zz = {0.f, 0.f, 0.f, 0.f};
      zz = __builtin_amdgcn_mfma_f32_16x16x32_bf16(A0.f, Bm[t][0].f, zz, 0, 0, 0);
      accM[t] = __builtin_amdgcn_mfma_f32_16x16x32_bf16(A1.f, Bm[t][1].f, zz, 0, 0, 0);
    }
#pragma unroll
    for (int t = 0; t < 4; ++t) {
      f32x4 zz = {0.f, 0.f, 0.f, 0.f};
      accS[t] = __builtin_amdgcn_mfma_f32_16x16x32_bf16(AS.f, Bs[t].f, zz, 0, 0, 0);
    }
#pragma unroll
    for (int q = 0; q < 4; ++q) {
      size_t node = (size_t)(nb + 4 * g + q);
      ushort* zp = z + node * 64 + r16;
      ushort* yp = y + node * 64 + r16;
#pragma unroll
      for (int t = 0; t < 4; ++t) {
        float zv = dq[q] * (accM[t][q] + bias4[t]) + accS[t][q];
        zp[t * 16] = f2bf_rne(zv);
        yp[t * 16] = f2bf_rne(accM[4 + t][q]);
      }
    }
  }
}

// ---- per-layer gather: R13 EXACT (wave-per-node, 8-deep ILP + serial tail) ----
#define GTB 25000
__global__ __launch_bounds__(256) void k_gath3(
    const __hip_bfloat16* __restrict__ y, const __hip_bfloat16* __restrict__ z,
    const unsigned* __restrict__ ebuf2, const int* __restrict__ rowptr,
    const float* __restrict__ gamma, const float* __restrict__ beta,
    __hip_bfloat16* __restrict__ xn, float* __restrict__ emb) {
  int lane = threadIdx.x & 63;
  int orig = blockIdx.x;
  int blk = (orig & 7) * (GTB / 8) + (orig >> 3);
  int n0 = blk * 4 + (threadIdx.x >> 6);
  if (n0 >= NN) return;
  int n = __builtin_amdgcn_readfirstlane(n0);
  int lo = rowptr[n], hi = rowptr[n + 1];
  int deg = hi - lo;
  int gb = (n / NPG) * NPG;
  const unsigned* cl = ebuf2 + lo;
  const __hip_bfloat16* yg = y + (size_t)gb * HH;
  float acc = __bfloat162float(z[(size_t)n * HH + lane]) +
              __bfloat162float(y[(size_t)n * HH + lane]);
  int k = 0;
  for (; k + 8 <= deg; k += 8) {
    int s0 = cl[k] & 1023, s1 = cl[k + 1] & 1023;
    int s2 = cl[k + 2] & 1023, s3 = cl[k + 3] & 1023;
    int s4 = cl[k + 4] & 1023, s5 = cl[k + 5] & 1023;
    int s6 = cl[k + 6] & 1023, s7 = cl[k + 7] & 1023;
    float v0 = __bfloat162float(yg[(size_t)s0 * HH + lane]);
    float v1 = __bfloat162float(yg[(size_t)s1 * HH + lane]);
    float v2 = __bfloat162float(yg[(size_t)s2 * HH + lane]);
    float v3 = __bfloat162float(yg[(size_t)s3 * HH + lane]);
    float v4 = __bfloat162float(yg[(size_t)s4 * HH + lane]);
    float v5 = __bfloat162float(yg[(size_t)s5 * HH + lane]);
    float v6 = __bfloat162float(yg[(size_t)s6 * HH + lane]);
    float v7 = __bfloat162float(yg[(size_t)s7 * HH + lane]);
    acc += ((v0 + v1) + (v2 + v3)) + ((v4 + v5) + (v6 + v7));
  }
  for (; k < deg; ++k)
    acc += __bfloat162float(yg[(size_t)(cl[k] & 1023) * HH + lane]);
  acc = fmaxf(acc, 0.f);
  acc = gamma[lane] * acc * BN_SCALE + beta[lane];
  acc = fmaxf(acc, 0.f);
  xn[(size_t)n * HH + lane] = __float2bfloat16(acc);
  if (n % NPG == 0) emb[(n / NPG) * HH + lane] = acc;
}

// ---- readout: FUSED pool + MLP (1024 threads: 16-wave pooling, 4-way fc1) ----
__global__ __launch_bounds__(1024) void k_final(
    const __hip_bfloat16* __restrict__ xf, const float* __restrict__ emb,
    const float* __restrict__ nbr, const float* __restrict__ fc1w,
    const float* __restrict__ fc1b, const float* __restrict__ fc2w,
    const float* __restrict__ fc2b, float* __restrict__ out) {
  __shared__ float pp[16][64];
  __shared__ float feats[320];
  __shared__ float r1p[4][256];
  __shared__ float red[4][4];
  int g = blockIdx.x;
  int t = threadIdx.x;
  int lane = t & 63, wv = t >> 6;
  const __hip_bfloat16* base = xf + (size_t)g * NPG * HH;
  float acc = 0.f;
  int i = wv;
  for (; i + 48 < NPG; i += 64) {
    float v0 = __bfloat162float(base[(size_t)i * HH + lane]);
    float v1 = __bfloat162float(base[(size_t)(i + 16) * HH + lane]);
    float v2 = __bfloat162float(base[(size_t)(i + 32) * HH + lane]);
    float v3 = __bfloat162float(base[(size_t)(i + 48) * HH + lane]);
    acc += (v0 + v1) + (v2 + v3);
  }
  for (; i < NPG; i += 16) acc += __bfloat162float(base[(size_t)i * HH + lane]);
  pp[wv][lane] = acc;
  __syncthreads();
  if (t < 64) {
    float s = 0.f;
#pragma unroll
    for (int w = 0; w < 16; ++w) s += pp[w][t];
    feats[t] = s;
    feats[256 + t] = nbr[(size_t)g * HH + t];
  } else if (t < 256) {
    int j = t - 64;
    feats[64 + j] = emb[((size_t)(j >> 6) * NG + g) * HH + (j & 63)];
  } else if (t < 384) {
    int j = t - 256 + 128;  // embs 128..255
    feats[64 + j] = emb[((size_t)(j >> 6) * NG + g) * HH + (j & 63)];
  }
  __syncthreads();
  int o = t & 255, tg = t >> 8;
  float a0 = 0.f, a1 = 0.f, a2 = 0.f, a3 = 0.f;
  const float* wp = fc1w + o;
  for (int k = tg * 80; k < tg * 80 + 80; k += 8) {
    float w0 = wp[(k + 0) * 256], w1 = wp[(k + 1) * 256];
    float w2 = wp[(k + 2) * 256], w3 = wp[(k + 3) * 256];
    float w4 = wp[(k + 4) * 256], w5 = wp[(k + 5) * 256];
    float w6 = wp[(k + 6) * 256], w7 = wp[(k + 7) * 256];
    a0 = fmaf(feats[k], w0, a0);
    a1 = fmaf(feats[k + 1], w1, a1);
    a2 = fmaf(feats[k + 2], w2, a2);
    a3 = fmaf(feats[k + 3], w3, a3);
    a0 = fmaf(feats[k + 4], w4, a0);
    a1 = fmaf(feats[k + 5], w5, a1);
    a2 = fmaf(feats[k + 6], w6, a2);
    a3 = fmaf(feats[k + 7], w7, a3);
  }
  r1p[tg][o] = (a0 + a1) + (a2 + a3);
  __syncthreads();
  if (t < 256) {
    float rv = fmaxf(fc1b[t] + ((r1p[0][t] + r1p[1][t]) + (r1p[2][t] + r1p[3][t])),
                     0.f);
    float p0 = rv * fc2w[t * 4 + 0];
    float p1 = rv * fc2w[t * 4 + 1];
    float p2 = rv * fc2w[t * 4 + 2];
    float p3 = rv * fc2w[t * 4 + 3];
#pragma unroll
    for (int oo = 1; oo < 64; oo <<= 1) {
      p0 += __shfl_xor(p0, oo);
      p1 += __shfl_xor(p1, oo);
      p2 += __shfl_xor(p2, oo);
      p3 += __shfl_xor(p3, oo);
    }
    if ((t & 63) == 0) {
      red[t >> 6][0] = p0; red[t >> 6][1] = p1;
      red[t >> 6][2] = p2; red[t >> 6][3] = p3;
    }
  }
  __syncthreads();
  if (t < 4)
    out[g * 4 + t] = fc2b[t] +
                     ((red[0][t] + red[1][t]) + (red[2][t] + red[3][t]));
}

extern "C" void kernel_launch(void* const* d_in, const int* in_sizes, int n_in,
                              void* d_out, int out_size, void* d_ws, size_t ws_size,
                              hipStream_t stream) {
  const float* x     = (const float*)d_in[0];
  const float* eattr = (const float*)d_in[1];
  const float* nbr   = (const float*)d_in[2];
  const float* W     = (const float*)d_in[3];
  const float* b     = (const float*)d_in[4];
  const float* gamma = (const float*)d_in[5];
  const float* beta  = (const float*)d_in[6];
  const float* fc1w  = (const float*)d_in[7];
  const float* fc1b  = (const float*)d_in[8];
  const float* fc2w  = (const float*)d_in[9];
  const float* fc2b  = (const float*)d_in[10];
  const int*   ei    = (const int*)d_in[11];
  float* out = (float*)d_out;
  (void)in_sizes; (void)n_in; (void)out_size; (void)ws_size;

  char* p = (char*)d_ws;
  size_t off = 0;
  auto alloc = [&](size_t bytes) {
    char* q = p + off;
    off += (bytes + 255) & ~(size_t)255;
    return q;
  };
  int* hist    = (int*)alloc((size_t)NB * NBIN * 4);  // [NBIN][NB] transposed
  int* partial = (int*)alloc((size_t)NB * NBIN * 4);
  int* gtot    = (int*)alloc((size_t)NBIN * 4);
  int* gbase   = (int*)alloc((size_t)(NBIN + 1) * 4);
  unsigned long long* ebuf = (unsigned long long*)alloc((size_t)NE * 8);
  unsigned* ebuf2 = (unsigned*)alloc((size_t)NE * 4);
  int* rowptr  = (int*)alloc((size_t)(NN + 1) * 4);
  ushort* Se16 = (ushort*)alloc((size_t)NN * 16 * 2);
  int*   cnt   = (int*)alloc((size_t)NN * 4);
  ushort* ybuf = (ushort*)alloc((size_t)NN * HH * 2);
  ushort* zbuf = (ushort*)alloc((size_t)NN * HH * 2);
  ushort* xA   = (ushort*)alloc((size_t)NN * HH * 2);
  ushort* xB   = (ushort*)alloc((size_t)NN * HH * 2);
  float* emb   = (float*)alloc((size_t)3 * NG * HH * 4);

  // CSR build via two-level counting sort (zero global f32 atomics, no fences)
  k_hist<<<NB, 256, 0, stream>>>(ei, hist);
  k_scan_a<<<NBIN, 512, 0, stream>>>(hist, partial, gtot);
  k_scan_b<<<1, 512, 0, stream>>>(gtot, gbase);
  k_bfill<<<NB, 256, 0, stream>>>(ei, partial, gbase, ebuf);
  k_nsort<<<NBIN, 1024, 0, stream>>>(ebuf, gbase, ebuf2, rowptr, cnt);
  k_se3<<<SEB, 256, 0, stream>>>(ebuf2, rowptr, eattr, Se16);

  // layer 0: x (f32) -> xA
  k_gemm<float><<<GB, 256, 0, stream>>>(x, W, b, cnt, Se16, ybuf, zbuf);
  k_gath3<<<GTB, 256, 0, stream>>>((const __hip_bfloat16*)ybuf,
                                   (const __hip_bfloat16*)zbuf, ebuf2, rowptr,
                                   gamma, beta, (__hip_bfloat16*)xA, emb);
  // layer 1: xA -> xB
  k_gemm<ushort><<<GB, 256, 0, stream>>>(xA, W + 144 * 64, b + 64, cnt, Se16,
                                         ybuf, zbuf);
  k_gath3<<<GTB, 256, 0, stream>>>((const __hip_bfloat16*)ybuf,
                                   (const __hip_bfloat16*)zbuf, ebuf2, rowptr,
                                   gamma + 64, beta + 64, (__hip_bfloat16*)xB,
                                   emb + NG * HH);
  // layer 2: xB -> xA
  k_gemm<ushort><<<GB, 256, 0, stream>>>(xB, W + 2 * 144 * 64, b + 128, cnt,
                                         Se16, ybuf, zbuf);
  k_gath3<<<GTB, 256, 0, stream>>>((const __hip_bfloat16*)ybuf,
                                   (const __hip_bfloat16*)zbuf, ebuf2, rowptr,
                                   gamma + 128, beta + 128, (__hip_bfloat16*)xA,
                                   emb + 2 * NG * HH);

  k_final<<<NG, 1024, 0, stream>>>((const __hip_bfloat16*)xA, emb, nbr, fc1w,
                                   fc1b, fc2w, fc2b, out);
}

// Round 21
// 245.923 us; speedup vs baseline: 1.8711x; 1.0020x over previous
//
#include <hip/hip_runtime.h>
#include <hip/hip_bf16.h>

#define NN 100000   // nodes
#define NE 1600000  // edges
#define NG 100      // graphs
#define NPG 1000    // nodes per graph
#define CE 16       // edge channels
#define HH 64       // hidden
#define BN_SCALE 0.99999500003749959f  // 1/sqrt(1+1e-5)
#define NB 512          // edge-chunk blocks
#define ECH (NE / NB)   // 3125 edges per chunk
#define NBIN 400        // dst bins: bin = dst/250 (4 bins per graph)

// LESSON (R3): f32 global atomicAdd on gfx950 = near-memory RMW (~35B HBM each).
// LESSON (R5): int global atomics ~40B each -> counting-sort CSR, no atomics.
// LESSON (R6/R16): per-edge work must be SPREAD ACROSS LANES; serial per-thread
// chains (16 LDS atomics, or one-edge-per-wave-instr) serialize ~10x.
// LESSON (R8): W "register cache" via LDS stays in LDS; use global loads.
// LESSON (R9): un-unrolled load+add loops serialize at L2/L3 latency.
// LESSON (R10): guarded loads serialize when occupancy is LOW; clamp+cndmask.
// LESSON (R11/R12): allocator targets 84 VGPR; s_load returns out-of-order.
// Node GEMMs belong on MFMA.
// LESSON (R13): give every build phase >=2k waves.
// LESSON (R14): wave-uniform scalar index loads are nearly free.
// LESSON (R15): at HIGH occupancy TLP hides serial tails.
// LESSON (R17): per-block __threadfence() x400 = 90us. Strided LOADS stall,
// strided STORES don't: scatter on the producer, coalesce the consumer.
// LESSON (R19): keep producer/consumer on the SAME XCD node ranges end-to-end.
// LESSON (R20): producer-side fusion of values already in registers (z+=y)
// is free; consumer-side loads are not.

typedef __attribute__((ext_vector_type(8))) short bf16x8;
typedef __attribute__((ext_vector_type(4))) float f32x4;
union ABu { bf16x8 f; ushort u[8]; };

__device__ __forceinline__ ushort f2bf_rne(float f) {
  unsigned u = __float_as_uint(f);
  return (ushort)((u + 0x7FFFu + ((u >> 16) & 1u)) >> 16);
}

// ---- phase 1: per-chunk histogram; TRANSPOSED store hist[bin][chunk] ----
__global__ __launch_bounds__(256) void k_hist(const int* __restrict__ ei,
                                              int* __restrict__ hist) {
  __shared__ int h[NBIN];
  for (int i = threadIdx.x; i < NBIN; i += 256) h[i] = 0;
  __syncthreads();
  int e0 = blockIdx.x * ECH;
  for (int i = threadIdx.x; i < ECH; i += 256) {
    int d = ei[NE + e0 + i];
    atomicAdd(&h[d / 250], 1);
  }
  __syncthreads();
  for (int i = threadIdx.x; i < NBIN; i += 256)
    hist[i * NB + blockIdx.x] = h[i];  // scattered store (fire-and-forget)
}

// ---- phase 2a: per-bin scan, COALESCED hist[bin][t] loads ----
__global__ __launch_bounds__(512) void k_scan_a(const int* __restrict__ hist,
                                                int* __restrict__ partial,
                                                int* __restrict__ gtot) {
  __shared__ int sv[512];
  int bin = blockIdx.x, t = threadIdx.x;
  int v = (t < NB) ? hist[bin * NB + t] : 0;
  sv[t] = v;
  __syncthreads();
  for (int o = 1; o < 512; o <<= 1) {
    int a = (t >= o) ? sv[t - o] : 0;
    __syncthreads();
    sv[t] += a;
    __syncthreads();
  }
  if (t < NB) partial[t * NBIN + bin] = sv[t] - v;
  if (t == 511) gtot[bin] = sv[511];
}

// ---- phase 2b: exclusive scan of the 400 bin totals -> segment bases ----
__global__ __launch_bounds__(512) void k_scan_b(const int* __restrict__ gtot,
                                                int* __restrict__ gbase) {
  __shared__ int sv[512];
  int t = threadIdx.x;
  int v = (t < NBIN) ? gtot[t] : 0;
  sv[t] = v;
  __syncthreads();
  for (int o = 1; o < 512; o <<= 1) {
    int a = (t >= o) ? sv[t - o] : 0;
    __syncthreads();
    sv[t] += a;
    __syncthreads();
  }
  if (t < NBIN) gbase[t] = sv[t] - v;
  if (t == 511) gbase[NBIN] = sv[511];
}

// ---- phase 3: scatter edges into bin segments (LDS cursors, 1x 8B store) ----
__global__ __launch_bounds__(256) void k_bfill(const int* __restrict__ ei,
                                               const int* __restrict__ partial,
                                               const int* __restrict__ gbase,
                                               unsigned long long* __restrict__ ebuf) {
  __shared__ int cur[NBIN];
  int b = blockIdx.x;
  for (int i = threadIdx.x; i < NBIN; i += 256)
    cur[i] = gbase[i] + partial[b * NBIN + i];
  __syncthreads();
  int e0 = b * ECH;
  for (int i = threadIdx.x; i < ECH; i += 256) {
    int e = e0 + i;
    int d = ei[NE + e], s = ei[e];
    int bin = d / 250;
    int gb = (bin >> 2) * 1000;
    unsigned long long pk = (unsigned long long)(unsigned)e << 32 |
                            (unsigned)((d - gb) << 10) | (unsigned)(s - gb);
    int pos = atomicAdd(&cur[bin], 1);
    ebuf[pos] = pk;
  }
}

// ---- phase 4: within-bin counting sort by node -> per-node CSR (1024 thr) ----
__global__ __launch_bounds__(1024) void k_nsort(
    const unsigned long long* __restrict__ ebuf, const int* __restrict__ gbase,
    unsigned* __restrict__ ebuf2, int* __restrict__ rowptr,
    int* __restrict__ cnt) {
  __shared__ int h[250];
  __shared__ int cur[250];
  __shared__ int sv[256];
  int bin = blockIdx.x, t = threadIdx.x;
  int nb = bin * 250, lbase = (bin & 3) * 250;
  int lo = gbase[bin], hi = gbase[bin + 1];
  if (t < 250) h[t] = 0;
  __syncthreads();
  for (int i = lo + t; i < hi; i += 1024) {
    int dl = (int)((ebuf[i] >> 10) & 1023);
    atomicAdd(&h[dl - lbase], 1);
  }
  __syncthreads();
  int v = (t < 250) ? h[t] : 0;
  if (t < 256) sv[t] = v;
  __syncthreads();
  for (int o = 1; o < 256; o <<= 1) {
    int a = (t < 256 && t >= o) ? sv[t - o] : 0;
    __syncthreads();
    if (t < 256) sv[t] += a;
    __syncthreads();
  }
  if (t < 250) {
    int base = lo + sv[t] - v;  // exclusive
    rowptr[nb + t] = base;
    cur[t] = base;
    cnt[nb + t] = v;
  }
  if (bin == NBIN - 1 && t == 0) rowptr[NN] = hi;
  __syncthreads();
  for (int i = lo + t; i < hi; i += 1024) {
    unsigned long long u = ebuf[i];
    int dl = (int)((u >> 10) & 1023);
    unsigned pk = (unsigned)(u >> 32) << 10 | (unsigned)(u & 1023);
    int pos = atomicAdd(&cur[dl - lbase], 1);
    ebuf2[pos] = pk;
  }
}

// ---- Se: wave-per-node float4 gather (R10 shape); PACKED BF16 [n][16] ----
#define SEB 25000
__global__ __launch_bounds__(256) void k_se3(const unsigned* __restrict__ ebuf2,
                                             const int* __restrict__ rowptr,
                                             const float* __restrict__ ea,
                                             ushort* __restrict__ Se16) {
  int lane = threadIdx.x & 63;
  int slot = lane >> 2;  // edge slot 0..15
  int q = lane & 3;      // row quarter (4 channels)
  int orig = blockIdx.x;
  int blk = (orig & 7) * (SEB / 8) + (orig >> 3);
  int n0 = blk * 4 + (threadIdx.x >> 6);
  if (n0 >= NN) return;
  int n = __builtin_amdgcn_readfirstlane(n0);
  int lo = rowptr[n], hi = rowptr[n + 1];
  float aA0 = 0.f, aA1 = 0.f, aA2 = 0.f, aA3 = 0.f;
  float aB0 = 0.f, aB1 = 0.f, aB2 = 0.f, aB3 = 0.f;
  for (int k0 = lo; k0 < hi; k0 += 32) {
    int ka = k0 + slot, kb = k0 + 16 + slot;
    int kca = min(ka, NE - 1), kcb = min(kb, NE - 1);
    unsigned eida = ebuf2[kca] >> 10;
    unsigned eidb = ebuf2[kcb] >> 10;
    float4 va = *(const float4*)(ea + (size_t)eida * CE + q * 4);
    float4 vb = *(const float4*)(ea + (size_t)eidb * CE + q * 4);
    bool oka = ka < hi, okb = kb < hi;
    aA0 += oka ? va.x : 0.f;
    aA1 += oka ? va.y : 0.f;
    aA2 += oka ? va.z : 0.f;
    aA3 += oka ? va.w : 0.f;
    aB0 += okb ? vb.x : 0.f;
    aB1 += okb ? vb.y : 0.f;
    aB2 += okb ? vb.z : 0.f;
    aB3 += okb ? vb.w : 0.f;
  }
  float r0 = aA0 + aB0, r1 = aA1 + aB1, r2 = aA2 + aB2, r3 = aA3 + aB3;
#pragma unroll
  for (int o = 4; o < 64; o <<= 1) {
    r0 += __shfl_xor(r0, o);
    r1 += __shfl_xor(r1, o);
    r2 += __shfl_xor(r2, o);
    r3 += __shfl_xor(r3, o);
  }
  if (lane < 4) {
    unsigned lo32 = (unsigned)f2bf_rne(r0) | ((unsigned)f2bf_rne(r1) << 16);
    unsigned hi32 = (unsigned)f2bf_rne(r2) | ((unsigned)f2bf_rne(r3) << 16);
    *(uint2*)(Se16 + (size_t)n * 16 + lane * 4) = make_uint2(lo32, hi32);
  }
}

// ------- per-layer node GEMM via MFMA; XCD-range tiles; z includes y (R20) --
#define GEMM_TILES (NN / 16)  // 6250
#define TPX 782               // tiles per XCD (ceil 6250/8)
#define GB 512                // 64 blocks -> 256 waves per XCD
template <typename T>
__global__ __attribute__((amdgpu_waves_per_eu(2, 4))) __launch_bounds__(256)
void k_gemm(const T* __restrict__ x, const float* __restrict__ W,
            const float* __restrict__ b, const int* __restrict__ cnt,
            const ushort* __restrict__ Se16, ushort* __restrict__ y,
            ushort* __restrict__ z) {
  int lane = threadIdx.x & 63;
  int g = lane >> 4, r16 = lane & 15;

  ABu Bm[8][2];
  ABu Bs[4];
  float bias4[4];
#pragma unroll
  for (int t = 0; t < 8; ++t) {
    int col = t * 16 + r16;
    const float* wbase = W + (col < 64 ? 0 : 64 * 64);
    int c64 = col & 63;
#pragma unroll
    for (int h = 0; h < 2; ++h)
#pragma unroll
      for (int e = 0; e < 8; ++e) {
        int k = h * 32 + (e < 4 ? 0 : 16) + 4 * g + (e & 3);
        Bm[t][h].u[e] = f2bf_rne(wbase[k * 64 + c64]);
      }
  }
#pragma unroll
  for (int t = 0; t < 4; ++t) {
    int col = t * 16 + r16;
    float ws = 0.f;
#pragma unroll
    for (int m = 0; m < 16; ++m) ws += W[(128 + m) * 64 + col];
#pragma unroll
    for (int e = 0; e < 8; ++e) {
      int k = (e < 4 ? 0 : 16) + 4 * g + (e & 3);
      float v = (k < 16) ? W[(128 + k) * 64 + col] : (k == 16 ? ws : 0.f);
      Bs[t].u[e] = f2bf_rne(v);
    }
    bias4[t] = b[col];
  }

  // XCD-range tile mapping: XCD i owns tiles [i*TPX, (i+1)*TPX)
  int xcd = blockIdx.x & 7;
  int wid = (blockIdx.x >> 3) * 4 + (threadIdx.x >> 6);  // 0..255 within XCD
  int tend = min((xcd + 1) * TPX, GEMM_TILES);
  for (int tt = xcd * TPX + wid; tt < tend; tt += (GB / 8) * 4) {
    int nb = tt * 16;
    ABu A0, A1, AS;
    if constexpr (sizeof(T) == 4) {
      const float* xr = (const float*)x + (size_t)(nb + r16) * HH;
      float4 f0 = *(const float4*)(xr + 4 * g);
      float4 f1 = *(const float4*)(xr + 16 + 4 * g);
      float4 f2 = *(const float4*)(xr + 32 + 4 * g);
      float4 f3 = *(const float4*)(xr + 48 + 4 * g);
      A0.u[0] = f2bf_rne(f0.x); A0.u[1] = f2bf_rne(f0.y);
      A0.u[2] = f2bf_rne(f0.z); A0.u[3] = f2bf_rne(f0.w);
      A0.u[4] = f2bf_rne(f1.x); A0.u[5] = f2bf_rne(f1.y);
      A0.u[6] = f2bf_rne(f1.z); A0.u[7] = f2bf_rne(f1.w);
      A1.u[0] = f2bf_rne(f2.x); A1.u[1] = f2bf_rne(f2.y);
      A1.u[2] = f2bf_rne(f2.z); A1.u[3] = f2bf_rne(f2.w);
      A1.u[4] = f2bf_rne(f3.x); A1.u[5] = f2bf_rne(f3.y);
      A1.u[6] = f2bf_rne(f3.z); A1.u[7] = f2bf_rne(f3.w);
    } else {
      const ushort* xr = (const ushort*)x + (size_t)(nb + r16) * HH;
      *(ushort4*)&A0.u[0] = *(const ushort4*)(xr + 4 * g);
      *(ushort4*)&A0.u[4] = *(const ushort4*)(xr + 16 + 4 * g);
      *(ushort4*)&A1.u[0] = *(const ushort4*)(xr + 32 + 4 * g);
      *(ushort4*)&A1.u[4] = *(const ushort4*)(xr + 48 + 4 * g);
    }
    const ushort* sr = Se16 + (size_t)(nb + r16) * 16;
    *(ushort4*)&AS.u[0] = *(const ushort4*)(sr + 4 * g);
    AS.u[4] = (g == 0) ? (ushort)0x3F80 : (ushort)0;  // k==16 -> 1.0
    AS.u[5] = 0; AS.u[6] = 0; AS.u[7] = 0;
    float dq[4];
#pragma unroll
    for (int q = 0; q < 4; ++q) dq[q] = (float)(cnt[nb + 4 * g + q] + 1);

    f32x4 accM[8], accS[4];
#pragma unroll
    for (int t = 0; t < 8; ++t) {
      f32x4 zz = {0.f, 0.f, 0.f, 0.f};
      zz = __builtin_amdgcn_mfma_f32_16x16x32_bf16(A0.f, Bm[t][0].f, zz, 0, 0, 0);
      accM[t] = __builtin_amdgcn_mfma_f32_16x16x32_bf16(A1.f, Bm[t][1].f, zz, 0, 0, 0);
    }
#pragma unroll
    for (int t = 0; t < 4; ++t) {
      f32x4 zz = {0.f, 0.f, 0.f, 0.f};
      accS[t] = __builtin_amdgcn_mfma_f32_16x16x32_bf16(AS.f, Bs[t].f, zz, 0, 0, 0);
    }
#pragma unroll
    for (int q = 0; q < 4; ++q) {
      size_t node = (size_t)(nb + 4 * g + q);
      ushort* zp = z + node * 64 + r16;
      ushort* yp = y + node * 64 + r16;
#pragma unroll
      for (int t = 0; t < 4; ++t) {
        float yv = accM[4 + t][q];
        // z' = local term + self-loop y (R20: fold y[n] into z at write time)
        float zv = dq[q] * (accM[t][q] + bias4[t]) + accS[t][q] + yv;
        zp[t * 16] = f2bf_rne(zv);
        yp[t * 16] = f2bf_rne(yv);
      }
    }
  }
}

// ---- per-layer gather: wave-per-node, 8-deep ILP; z already includes y[n] ----
#define GTB 25000
__global__ __launch_bounds__(256) void k_gath3(
    const __hip_bfloat16* __restrict__ y, const __hip_bfloat16* __restrict__ z,
    const unsigned* __restrict__ ebuf2, const int* __restrict__ rowptr,
    const float* __restrict__ gamma, const float* __restrict__ beta,
    __hip_bfloat16* __restrict__ xn, float* __restrict__ emb) {
  int lane = threadIdx.x & 63;
  int orig = blockIdx.x;
  int blk = (orig & 7) * (GTB / 8) + (orig >> 3);
  int n0 = blk * 4 + (threadIdx.x >> 6);
  if (n0 >= NN) return;
  int n = __builtin_amdgcn_readfirstlane(n0);
  int lo = rowptr[n], hi = rowptr[n + 1];
  int deg = hi - lo;
  int gb = (n / NPG) * NPG;
  const unsigned* cl = ebuf2 + lo;
  const __hip_bfloat16* yg = y + (size_t)gb * HH;
  float acc = __bfloat162float(z[(size_t)n * HH + lane]);  // incl. self-loop y
  int k = 0;
  for (; k + 8 <= deg; k += 8) {
    int s0 = cl[k] & 1023, s1 = cl[k + 1] & 1023;
    int s2 = cl[k + 2] & 1023, s3 = cl[k + 3] & 1023;
    int s4 = cl[k + 4] & 1023, s5 = cl[k + 5] & 1023;
    int s6 = cl[k + 6] & 1023, s7 = cl[k + 7] & 1023;
    float v0 = __bfloat162float(yg[(size_t)s0 * HH + lane]);
    float v1 = __bfloat162float(yg[(size_t)s1 * HH + lane]);
    float v2 = __bfloat162float(yg[(size_t)s2 * HH + lane]);
    float v3 = __bfloat162float(yg[(size_t)s3 * HH + lane]);
    float v4 = __bfloat162float(yg[(size_t)s4 * HH + lane]);
    float v5 = __bfloat162float(yg[(size_t)s5 * HH + lane]);
    float v6 = __bfloat162float(yg[(size_t)s6 * HH + lane]);
    float v7 = __bfloat162float(yg[(size_t)s7 * HH + lane]);
    acc += ((v0 + v1) + (v2 + v3)) + ((v4 + v5) + (v6 + v7));
  }
  for (; k < deg; ++k)
    acc += __bfloat162float(yg[(size_t)(cl[k] & 1023) * HH + lane]);
  acc = fmaxf(acc, 0.f);
  acc = gamma[lane] * acc * BN_SCALE + beta[lane];
  acc = fmaxf(acc, 0.f);
  xn[(size_t)n * HH + lane] = __float2bfloat16(acc);
  if (n % NPG == 0) emb[(n / NPG) * HH + lane] = acc;
}

// ---- readout: FUSED pool + MLP (1024 threads: 16-wave pooling, 4-way fc1) ----
__global__ __launch_bounds__(1024) void k_final(
    const __hip_bfloat16* __restrict__ xf, const float* __restrict__ emb,
    const float* __restrict__ nbr, const float* __restrict__ fc1w,
    const float* __restrict__ fc1b, const float* __restrict__ fc2w,
    const float* __restrict__ fc2b, float* __restrict__ out) {
  __shared__ float pp[16][64];
  __shared__ float feats[320];
  __shared__ float r1p[4][256];
  __shared__ float red[4][4];
  int g = blockIdx.x;
  int t = threadIdx.x;
  int lane = t & 63, wv = t >> 6;
  const __hip_bfloat16* base = xf + (size_t)g * NPG * HH;
  float acc = 0.f;
  int i = wv;
  for (; i + 48 < NPG; i += 64) {
    float v0 = __bfloat162float(base[(size_t)i * HH + lane]);
    float v1 = __bfloat162float(base[(size_t)(i + 16) * HH + lane]);
    float v2 = __bfloat162float(base[(size_t)(i + 32) * HH + lane]);
    float v3 = __bfloat162float(base[(size_t)(i + 48) * HH + lane]);
    acc += (v0 + v1) + (v2 + v3);
  }
  for (; i < NPG; i += 16) acc += __bfloat162float(base[(size_t)i * HH + lane]);
  pp[wv][lane] = acc;
  __syncthreads();
  if (t < 64) {
    float s = 0.f;
#pragma unroll
    for (int w = 0; w < 16; ++w) s += pp[w][t];
    feats[t] = s;
    feats[256 + t] = nbr[(size_t)g * HH + t];
  } else if (t < 256) {
    int j = t - 64;
    feats[64 + j] = emb[((size_t)(j >> 6) * NG + g) * HH + (j & 63)];
  } else if (t < 384) {
    int j = t - 256 + 128;  // embs 128..255
    feats[64 + j] = emb[((size_t)(j >> 6) * NG + g) * HH + (j & 63)];
  }
  __syncthreads();
  int o = t & 255, tg = t >> 8;
  float a0 = 0.f, a1 = 0.f, a2 = 0.f, a3 = 0.f;
  const float* wp = fc1w + o;
  for (int k = tg * 80; k < tg * 80 + 80; k += 8) {
    float w0 = wp[(k + 0) * 256], w1 = wp[(k + 1) * 256];
    float w2 = wp[(k + 2) * 256], w3 = wp[(k + 3) * 256];
    float w4 = wp[(k + 4) * 256], w5 = wp[(k + 5) * 256];
    float w6 = wp[(k + 6) * 256], w7 = wp[(k + 7) * 256];
    a0 = fmaf(feats[k], w0, a0);
    a1 = fmaf(feats[k + 1], w1, a1);
    a2 = fmaf(feats[k + 2], w2, a2);
    a3 = fmaf(feats[k + 3], w3, a3);
    a0 = fmaf(feats[k + 4], w4, a0);
    a1 = fmaf(feats[k + 5], w5, a1);
    a2 = fmaf(feats[k + 6], w6, a2);
    a3 = fmaf(feats[k + 7], w7, a3);
  }
  r1p[tg][o] = (a0 + a1) + (a2 + a3);
  __syncthreads();
  if (t < 256) {
    float rv = fmaxf(fc1b[t] + ((r1p[0][t] + r1p[1][t]) + (r1p[2][t] + r1p[3][t])),
                     0.f);
    float p0 = rv * fc2w[t * 4 + 0];
    float p1 = rv * fc2w[t * 4 + 1];
    float p2 = rv * fc2w[t * 4 + 2];
    float p3 = rv * fc2w[t * 4 + 3];
#pragma unroll
    for (int oo = 1; oo < 64; oo <<= 1) {
      p0 += __shfl_xor(p0, oo);
      p1 += __shfl_xor(p1, oo);
      p2 += __shfl_xor(p2, oo);
      p3 += __shfl_xor(p3, oo);
    }
    if ((t & 63) == 0) {
      red[t >> 6][0] = p0; red[t >> 6][1] = p1;
      red[t >> 6][2] = p2; red[t >> 6][3] = p3;
    }
  }
  __syncthreads();
  if (t < 4)
    out[g * 4 + t] = fc2b[t] +
                     ((red[0][t] + red[1][t]) + (red[2][t] + red[3][t]));
}

extern "C" void kernel_launch(void* const* d_in, const int* in_sizes, int n_in,
                              void* d_out, int out_size, void* d_ws, size_t ws_size,
                              hipStream_t stream) {
  const float* x     = (const float*)d_in[0];
  const float* eattr = (const float*)d_in[1];
  const float* nbr   = (const float*)d_in[2];
  const float* W     = (const float*)d_in[3];
  const float* b     = (const float*)d_in[4];
  const float* gamma = (const float*)d_in[5];
  const float* beta  = (const float*)d_in[6];
  const float* fc1w  = (const float*)d_in[7];
  const float* fc1b  = (const float*)d_in[8];
  const float* fc2w  = (const float*)d_in[9];
  const float* fc2b  = (const float*)d_in[10];
  const int*   ei    = (const int*)d_in[11];
  float* out = (float*)d_out;
  (void)in_sizes; (void)n_in; (void)out_size; (void)ws_size;

  char* p = (char*)d_ws;
  size_t off = 0;
  auto alloc = [&](size_t bytes) {
    char* q = p + off;
    off += (bytes + 255) & ~(size_t)255;
    return q;
  };
  int* hist    = (int*)alloc((size_t)NB * NBIN * 4);  // [NBIN][NB] transposed
  int* partial = (int*)alloc((size_t)NB * NBIN * 4);
  int* gtot    = (int*)alloc((size_t)NBIN * 4);
  int* gbase   = (int*)alloc((size_t)(NBIN + 1) * 4);
  unsigned long long* ebuf = (unsigned long long*)alloc((size_t)NE * 8);
  unsigned* ebuf2 = (unsigned*)alloc((size_t)NE * 4);
  int* rowptr  = (int*)alloc((size_t)(NN + 1) * 4);
  ushort* Se16 = (ushort*)alloc((size_t)NN * 16 * 2);
  int*   cnt   = (int*)alloc((size_t)NN * 4);
  ushort* ybuf = (ushort*)alloc((size_t)NN * HH * 2);
  ushort* zbuf = (ushort*)alloc((size_t)NN * HH * 2);
  ushort* xA   = (ushort*)alloc((size_t)NN * HH * 2);
  ushort* xB   = (ushort*)alloc((size_t)NN * HH * 2);
  float* emb   = (float*)alloc((size_t)3 * NG * HH * 4);

  // CSR build via two-level counting sort (zero global f32 atomics, no fences)
  k_hist<<<NB, 256, 0, stream>>>(ei, hist);
  k_scan_a<<<NBIN, 512, 0, stream>>>(hist, partial, gtot);
  k_scan_b<<<1, 512, 0, stream>>>(gtot, gbase);
  k_bfill<<<NB, 256, 0, stream>>>(ei, partial, gbase, ebuf);
  k_nsort<<<NBIN, 1024, 0, stream>>>(ebuf, gbase, ebuf2, rowptr, cnt);
  k_se3<<<SEB, 256, 0, stream>>>(ebuf2, rowptr, eattr, Se16);

  // layer 0: x (f32) -> xA
  k_gemm<float><<<GB, 256, 0, stream>>>(x, W, b, cnt, Se16, ybuf, zbuf);
  k_gath3<<<GTB, 256, 0, stream>>>((const __hip_bfloat16*)ybuf,
                                   (const __hip_bfloat16*)zbuf, ebuf2, rowptr,
                                   gamma, beta, (__hip_bfloat16*)xA, emb);
  // layer 1: xA -> xB
  k_gemm<ushort><<<GB, 256, 0, stream>>>(xA, W + 144 * 64, b + 64, cnt, Se16,
                                         ybuf, zbuf);
  k_gath3<<<GTB, 256, 0, stream>>>((const __hip_bfloat16*)ybuf,
                                   (const __hip_bfloat16*)zbuf, ebuf2, rowptr,
                                   gamma + 64, beta + 64, (__hip_bfloat16*)xB,
                                   emb + NG * HH);
  // layer 2: xB -> xA
  k_gemm<ushort><<<GB, 256, 0, stream>>>(xB, W + 2 * 144 * 64, b + 128, cnt,
                                         Se16, ybuf, zbuf);
  k_gath3<<<GTB, 256, 0, stream>>>((const __hip_bfloat16*)ybuf,
                                   (const __hip_bfloat16*)zbuf, ebuf2, rowptr,
                                   gamma + 128, beta + 128, (__hip_bfloat16*)xA,
                                   emb + 2 * NG * HH);

  k_final<<<NG, 1024, 0, stream>>>((const __hip_bfloat16*)xA, emb, nbr, fc1w,
                                   fc1b, fc2w, fc2b, out);
}